// Round 7
// baseline (44.406 us; speedup 1.0000x reference)
//
#include <hip/hip_runtime.h>
#include <math.h>

#define NQ 9
#define NL 5
#define NC 10

typedef float v2f __attribute__((ext_vector_type(2)));
typedef float v4f __attribute__((ext_vector_type(4)));

__device__ __forceinline__ v2f sp(float x) { v2f r; r.x = x; r.y = x; return r; }

// ---- gfx950 permlane swap: feed x to both operands.
// v_permlane32_swap(vdst=a, src0=b) -> out0 = {a.lo, b.lo}, out1 = {a.hi, b.hi}.
// With a=b=x:  r[0][i] = x[i & ~M] (lo-broadcast), r[1][i] = x[i | M] (hi-broadcast).
// Same orientation for permlane16_swap. Pure VALU.
__device__ __forceinline__ void swpm(float x, int mask, float& hi, float& lo) {
    if (mask == 32) {
        auto r = __builtin_amdgcn_permlane32_swap(__float_as_int(x), __float_as_int(x), false, false);
        lo = __int_as_float(r[0]); hi = __int_as_float(r[1]);
    } else {
        auto r = __builtin_amdgcn_permlane16_swap(__float_as_int(x), __float_as_int(x), false, false);
        lo = __int_as_float(r[0]); hi = __int_as_float(r[1]);
    }
}
__device__ __forceinline__ void swpm2(v2f x, int mask, v2f& hi, v2f& lo) {
    float hx, lx, hy, ly;
    swpm(x.x, mask, hx, lx);
    swpm(x.y, mask, hy, ly);
    hi.x = hx; hi.y = hy; lo.x = lx; lo.y = ly;
}

// XOR-lane exchange for masks 1,2,4,8 — DPP only (VALU).
__device__ __forceinline__ float xmove(float x, int mask) {
    if (mask == 1)
        return __int_as_float(__builtin_amdgcn_update_dpp(0, __float_as_int(x), 0xB1, 0xF, 0xF, true));
    if (mask == 2)
        return __int_as_float(__builtin_amdgcn_update_dpp(0, __float_as_int(x), 0x4E, 0xF, 0xF, true));
    if (mask == 4) {
        int t = __builtin_amdgcn_update_dpp(0, __float_as_int(x), 0x104, 0xF, 0x5, false); // row_shl:4 banks 0,2
        t = __builtin_amdgcn_update_dpp(t, __float_as_int(x), 0x114, 0xF, 0xA, false);     // row_shr:4 banks 1,3
        return __int_as_float(t);
    }
    return __int_as_float(__builtin_amdgcn_update_dpp(0, __float_as_int(x), 0x128, 0xF, 0xF, true)); // row_ror:8
}
__device__ __forceinline__ v2f xmv2(v2f v, int mask) {
    v2f r; r.x = xmove(v.x, mask); r.y = xmove(v.y, mask); return r;
}

// State packing: lane owns 8 amps as 4 x float2; amp = (j<<1)|comp.
// wire w -> bit 8-w: wires 0..5 -> lane bits 5..0; wire6 -> j bit1; wire7 -> j bit0; wire8 -> comp.

// U = Rot*RX entries from m[8] = {m00r,m00i,m01r,m01i,m10r,m10i,m11r,m11i}
#define FUSED_U(A, Bq, c, s)                                          \
    float u00r = A.x*c + s*A.w,  u00i = A.y*c - s*A.z;                \
    float u01r = A.z*c + s*A.y,  u01i = A.w*c - s*A.x;                \
    float u10r = Bq.x*c + s*Bq.w, u10i = Bq.y*c - s*Bq.z;             \
    float u11r = Bq.z*c + s*Bq.y, u11i = Bq.w*c - s*Bq.x;

// ---- fused (Rot*RX) on lane bit LB in {4,5}: column form via permlane (no LDS) ----
template<int LB>
__device__ __forceinline__ void fused_cross_hl(v2f (&xr)[4], v2f (&xi)[4],
                                               const float* __restrict__ m,
                                               float c, float s, int lane) {
    const v4f A = *(const v4f*)m; const v4f Bq = *(const v4f*)(m + 4);
    FUSED_U(A, Bq, c, s)
    const int bit = (lane >> LB) & 1;
    const float Clr = bit ? u10r : u00r, Cli = bit ? u10i : u00i;  // coeff of lo (col 0)
    const float Chr = bit ? u11r : u01r, Chi = bit ? u11i : u01i;  // coeff of hi (col 1)
    const int MK = 1 << LB;
#pragma unroll
    for (int j = 0; j < 4; ++j) {
        v2f hr, lr, hi2, li;
        swpm2(xr[j], MK, hr, lr);
        swpm2(xi[j], MK, hi2, li);
        xr[j] = sp(Clr)*lr - sp(Cli)*li + sp(Chr)*hr - sp(Chi)*hi2;
        xi[j] = sp(Clr)*li + sp(Cli)*lr + sp(Chr)*hi2 + sp(Chi)*hr;
    }
}

// ---- fused (Rot*RX) on lane bit LB in {0..3}: DPP self/partner form ----
template<int LB>
__device__ __forceinline__ void fused_cross_dpp(v2f (&xr)[4], v2f (&xi)[4],
                                                const float* __restrict__ m,
                                                float c, float s, int lane) {
    const v4f A = *(const v4f*)m; const v4f Bq = *(const v4f*)(m + 4);
    FUSED_U(A, Bq, c, s)
    const int bit = (lane >> LB) & 1;
    const float Csr = bit ? u11r : u00r, Csi = bit ? u11i : u00i;  // self
    const float Cpr = bit ? u10r : u01r, Cpi = bit ? u10i : u01i;  // partner
#pragma unroll
    for (int j = 0; j < 4; ++j) {
        v2f pr = xmv2(xr[j], 1 << LB);
        v2f pi = xmv2(xi[j], 1 << LB);
        v2f ar = xr[j], ai = xi[j];
        xr[j] = sp(Csr)*ar - sp(Csi)*ai + sp(Cpr)*pr - sp(Cpi)*pi;
        xi[j] = sp(Csr)*ai + sp(Csi)*ar + sp(Cpr)*pi + sp(Cpi)*pr;
    }
}

// ---- fused (Rot*RX) on a j bit (wires 6,7) ----
template<int JB>
__device__ __forceinline__ void fused_local_j(v2f (&xr)[4], v2f (&xi)[4],
                                              const float* __restrict__ m,
                                              float c, float s) {
    const v4f A = *(const v4f*)m; const v4f Bq = *(const v4f*)(m + 4);
    FUSED_U(A, Bq, c, s)
#pragma unroll
    for (int j = 0; j < 4; ++j) {
        if ((j >> JB) & 1) continue;
        const int j1 = j | (1 << JB);
        v2f a0r = xr[j], a0i = xi[j], a1r = xr[j1], a1i = xi[j1];
        xr[j]  = sp(u00r)*a0r - sp(u00i)*a0i + sp(u01r)*a1r - sp(u01i)*a1i;
        xi[j]  = sp(u00r)*a0i + sp(u00i)*a0r + sp(u01r)*a1i + sp(u01i)*a1r;
        xr[j1] = sp(u10r)*a0r - sp(u10i)*a0i + sp(u11r)*a1r - sp(u11i)*a1i;
        xi[j1] = sp(u10r)*a0i + sp(u10i)*a0r + sp(u11r)*a1i + sp(u11i)*a1r;
    }
}

// ---- fused (Rot*RX) on the component bit (wire 8): broadcast form ----
__device__ __forceinline__ void fused_local_c(v2f (&xr)[4], v2f (&xi)[4],
                                              const float* __restrict__ m,
                                              float c, float s) {
    const v4f A = *(const v4f*)m; const v4f Bq = *(const v4f*)(m + 4);
    v2f U0r = { A.x*c + s*A.w,  Bq.x*c + s*Bq.w };
    v2f U0i = { A.y*c - s*A.z,  Bq.y*c - s*Bq.z };
    v2f U1r = { A.z*c + s*A.y,  Bq.z*c + s*Bq.y };
    v2f U1i = { A.w*c - s*A.x,  Bq.w*c - s*Bq.x };
#pragma unroll
    for (int j = 0; j < 4; ++j) {
        v2f A0r = xr[j].xx, A0i = xi[j].xx, A1r = xr[j].yy, A1i = xi[j].yy;
        xr[j] = U0r*A0r - U0i*A0i + U1r*A1r - U1i*A1i;
        xi[j] = U0r*A0i + U0i*A0r + U1r*A1i + U1i*A1r;
    }
}

// ---- CRX: ctrl lane bit CB, tgt lane-mask M in {16,32}: permlane + sl/sh split ----
template<int CB, int M>
__device__ __forceinline__ void crx_hl(v2f (&xr)[4], v2f (&xi)[4], float c, float s, int lane) {
    const bool ctrl = (lane >> CB) & 1;
    const float ce = ctrl ? c : 1.f;
    const float se = ctrl ? s : 0.f;
    const bool tbit = lane & M;
    const float sl = tbit ? se : 0.f;   // partner is lo when my tgt bit = 1
    const float sh = tbit ? 0.f : se;
#pragma unroll
    for (int j = 0; j < 4; ++j) {
        v2f hr, lr, hi2, li;
        swpm2(xr[j], M, hr, lr);
        swpm2(xi[j], M, hi2, li);
        xr[j] = sp(ce)*xr[j] + sp(sl)*li + sp(sh)*hi2;
        xi[j] = sp(ce)*xi[j] - sp(sl)*lr - sp(sh)*hr;
    }
}

// ---- CRX: ctrl lane bit CB, tgt lane-mask M in {1,2,4,8}: DPP ----
template<int CB, int M>
__device__ __forceinline__ void crx_dpp(v2f (&xr)[4], v2f (&xi)[4], float c, float s, int lane) {
    const bool ctrl = (lane >> CB) & 1;
    const float ce = ctrl ? c : 1.f;
    const float se = ctrl ? s : 0.f;
#pragma unroll
    for (int j = 0; j < 4; ++j) {
        v2f pr = xmv2(xr[j], M);
        v2f pi = xmv2(xi[j], M);
        xr[j] = sp(ce)*xr[j] + sp(se)*pi;
        xi[j] = sp(ce)*xi[j] - sp(se)*pr;
    }
}

// ---- CRX w=5: ctrl lane bit0 (wire5), tgt j bit1 (wire6) ----
__device__ __forceinline__ void crx_l_j1(v2f (&xr)[4], v2f (&xi)[4], float c, float s, int lane) {
    const bool ctrl = lane & 1;
    const float ce = ctrl ? c : 1.f;
    const float se = ctrl ? s : 0.f;
#pragma unroll
    for (int j = 0; j < 2; ++j) {
        const int j1 = j | 2;
        v2f a0r = xr[j], a0i = xi[j], a1r = xr[j1], a1i = xi[j1];
        xr[j]  = sp(ce)*a0r + sp(se)*a1i;
        xi[j]  = sp(ce)*a0i - sp(se)*a1r;
        xr[j1] = sp(ce)*a1r + sp(se)*a0i;
        xi[j1] = sp(ce)*a1i - sp(se)*a0r;
    }
}

// ---- CRX w=6: ctrl j bit1, tgt j bit0: pair (2,3) ----
__device__ __forceinline__ void crx_j1_j0(v2f (&xr)[4], v2f (&xi)[4], float c, float s) {
    v2f a0r = xr[2], a0i = xi[2], a1r = xr[3], a1i = xi[3];
    xr[2] = sp(c)*a0r + sp(s)*a1i;
    xi[2] = sp(c)*a0i - sp(s)*a1r;
    xr[3] = sp(c)*a1r + sp(s)*a0i;
    xi[3] = sp(c)*a1i - sp(s)*a0r;
}

// ---- CRX w=7: ctrl j bit0 (j in {1,3}), tgt component ----
__device__ __forceinline__ void crx_j0_c(v2f (&xr)[4], v2f (&xi)[4], float c, float s) {
#pragma unroll
    for (int j = 1; j < 4; j += 2) {
        v2f vr = xr[j], vi = xi[j];
        xr[j] = sp(c)*vr + sp(s)*vi.yx;
        xi[j] = sp(c)*vi - sp(s)*vr.yx;
    }
}

// ---- CRX w=8: ctrl component (wire8), tgt lane bit5 (wire0, mask 32) ----
__device__ __forceinline__ void crx_c_l5(v2f (&xr)[4], v2f (&xi)[4], float c, float s, int lane) {
    const v2f cev = {1.f, c};
    const v2f sev = {0.f, s};
    const v2f zv  = {0.f, 0.f};
    const bool tbit = lane & 32;
    const v2f sl = tbit ? sev : zv;
    const v2f sh = tbit ? zv : sev;
#pragma unroll
    for (int j = 0; j < 4; ++j) {
        v2f hr, lr, hi2, li;
        swpm2(xr[j], 32, hr, lr);
        swpm2(xi[j], 32, hi2, li);
        xr[j] = cev*xr[j] + sl*li + sh*hi2;
        xi[j] = cev*xi[j] - sl*lr - sh*hr;
    }
}

__global__ __launch_bounds__(256) void qmlp_kernel(
    const float* __restrict__ x, const float* __restrict__ rot_w,
    const float* __restrict__ crx_w, const float* __restrict__ fc_w,
    const float* __restrict__ fc_b, float* __restrict__ out, int B)
{
    __shared__ __align__(16) float rotm[NL * NQ * 8];
    __shared__ __align__(16) float crxm[NL * NQ * 2];
    __shared__ float fcw[NC * NQ];
    __shared__ float fcbs[NC];

    const int tid = threadIdx.x;
    if (tid < NL * NQ) {
        const float phi = rot_w[tid * 3 + 0];
        const float th  = rot_w[tid * 3 + 1];
        const float om  = rot_w[tid * 3 + 2];
        float st, ct; sincosf(0.5f * th, &st, &ct);
        float spo, cpo; sincosf(0.5f * (phi + om), &spo, &cpo);
        float smo, cmo; sincosf(0.5f * (phi - om), &smo, &cmo);
        float* m = rotm + tid * 8;
        m[0] =  ct * cpo; m[1] = -ct * spo;
        m[2] = -st * cmo; m[3] = -st * smo;
        m[4] =  st * cmo; m[5] = -st * smo;
        m[6] =  ct * cpo; m[7] =  ct * spo;
        float sc, cc; sincosf(0.5f * crx_w[tid], &sc, &cc);
        crxm[tid * 2 + 0] = cc; crxm[tid * 2 + 1] = sc;
    }
    if (tid < NC * NQ) fcw[tid] = fc_w[tid];
    if (tid < NC) fcbs[tid] = fc_b[tid];
    __syncthreads();

    const int lane = tid & 63;
    const int b = blockIdx.x * 4 + (tid >> 6);
    if (b >= B) return;

    float cx[NQ], sx[NQ];
#pragma unroll
    for (int w = 0; w < NQ; ++w) __sincosf(0.5f * x[b * NQ + w], &sx[w], &cx[w]);

    v2f xr[4], xi[4];

    // ---- Layer 0 single-qubit block on |0..0>: direct product state ----
    {
        const float* M = rotm;
        float ar = 1.f, ai = 0.f;
#pragma unroll
        for (int w = 0; w < 6; ++w) {
            const float* m = M + w * 8;
            float c = cx[w], s = sx[w];
            int bit = (lane >> (5 - w)) & 1;
            float u0r = m[0]*c + s*m[3], u0i = m[1]*c - s*m[2];
            float u1r = m[4]*c + s*m[7], u1i = m[5]*c - s*m[6];
            float vr = bit ? u1r : u0r;
            float vi = bit ? u1i : u0i;
            float nr = ar * vr - ai * vi;
            float ni = ar * vi + ai * vr;
            ar = nr; ai = ni;
        }
        float vr67[2][2], vi67[2][2];
#pragma unroll
        for (int q = 0; q < 2; ++q) {
            const float* m = M + (6 + q) * 8;
            float c = cx[6 + q], s = sx[6 + q];
            vr67[q][0] = m[0]*c + s*m[3]; vi67[q][0] = m[1]*c - s*m[2];
            vr67[q][1] = m[4]*c + s*m[7]; vi67[q][1] = m[5]*c - s*m[6];
        }
        float t6r[2], t6i[2];
#pragma unroll
        for (int bb = 0; bb < 2; ++bb) {
            t6r[bb] = ar * vr67[0][bb] - ai * vi67[0][bb];
            t6i[bb] = ar * vi67[0][bb] + ai * vr67[0][bb];
        }
        float t67r[4], t67i[4];
#pragma unroll
        for (int j = 0; j < 4; ++j) {
            int b6 = j >> 1, b7 = j & 1;
            t67r[j] = t6r[b6] * vr67[1][b7] - t6i[b6] * vi67[1][b7];
            t67i[j] = t6r[b6] * vi67[1][b7] + t6i[b6] * vr67[1][b7];
        }
        const float* m8 = M + 8 * 8;
        float c8 = cx[8], s8 = sx[8];
        v2f V8r = { m8[0]*c8 + s8*m8[3], m8[4]*c8 + s8*m8[7] };
        v2f V8i = { m8[1]*c8 - s8*m8[2], m8[5]*c8 - s8*m8[6] };
#pragma unroll
        for (int j = 0; j < 4; ++j) {
            xr[j] = sp(t67r[j])*V8r - sp(t67i[j])*V8i;
            xi[j] = sp(t67r[j])*V8i + sp(t67i[j])*V8r;
        }
    }

    // ---- Layer 0 CRX ring + layers 1..4 ----
    for (int n = 0; n < NL; ++n) {
        if (n > 0) {
            const float* M = rotm + n * NQ * 8;
            fused_cross_hl<5>(xr, xi, M + 0 * 8, cx[0], sx[0], lane);   // wire0: mask32 permlane
            fused_cross_hl<4>(xr, xi, M + 1 * 8, cx[1], sx[1], lane);   // wire1: mask16 permlane
            fused_cross_dpp<3>(xr, xi, M + 2 * 8, cx[2], sx[2], lane);
            fused_cross_dpp<2>(xr, xi, M + 3 * 8, cx[3], sx[3], lane);
            fused_cross_dpp<1>(xr, xi, M + 4 * 8, cx[4], sx[4], lane);
            fused_cross_dpp<0>(xr, xi, M + 5 * 8, cx[5], sx[5], lane);
            fused_local_j<1>(xr, xi, M + 6 * 8, cx[6], sx[6]);
            fused_local_j<0>(xr, xi, M + 7 * 8, cx[7], sx[7]);
            fused_local_c   (xr, xi, M + 8 * 8, cx[8], sx[8]);
        }
        const float* C = crxm + n * NQ * 2;
        crx_hl<5, 16>(xr, xi, C[0],  C[1],  lane);  // w=0: tgt wire1 (mask16)
        crx_dpp<4, 8>(xr, xi, C[2],  C[3],  lane);  // w=1
        crx_dpp<3, 4>(xr, xi, C[4],  C[5],  lane);  // w=2
        crx_dpp<2, 2>(xr, xi, C[6],  C[7],  lane);  // w=3
        crx_dpp<1, 1>(xr, xi, C[8],  C[9],  lane);  // w=4
        crx_l_j1     (xr, xi, C[10], C[11], lane);  // w=5
        crx_j1_j0    (xr, xi, C[12], C[13]);        // w=6
        crx_j0_c     (xr, xi, C[14], C[15]);        // w=7
        crx_c_l5     (xr, xi, C[16], C[17], lane);  // w=8: tgt wire0 (mask32)
    }

    // ---- probabilities and <Z_w> ----
    v2f P[4];
#pragma unroll
    for (int j = 0; j < 4; ++j) P[j] = xr[j]*xr[j] + xi[j]*xi[j];
    float ps[4];
#pragma unroll
    for (int j = 0; j < 4; ++j) ps[j] = P[j].x + P[j].y;
    float psum = ps[0] + ps[1] + ps[2] + ps[3];

    // lane-bit <Z>'s: shared-prefix signed reduction; masks 16/32 via permlane pair
    float t = psum;
    float d[6];
#pragma unroll
    for (int bb = 0; bb < 6; ++bb) {
        if (bb < 4) {
#pragma unroll
            for (int jj = 0; jj < 6; ++jj)
                if (jj < bb) d[jj] += xmove(d[jj], 1 << bb);
            float o = xmove(t, 1 << bb);
            d[bb] = ((lane >> bb) & 1) ? (o - t) : (t - o);
            t += o;
        } else {
#pragma unroll
            for (int jj = 0; jj < 6; ++jj)
                if (jj < bb) { float h, l; swpm(d[jj], 1 << bb, h, l); d[jj] = h + l; }
            float h, l; swpm(t, 1 << bb, h, l);
            d[bb] = l - h;    // sum(bit=0 half) - sum(bit=1 half), valid in all lanes
            t = h + l;
        }
    }
    // local-bit <Z>'s
    float e6 = (ps[0] + ps[1]) - (ps[2] + ps[3]);
    float e7 = (ps[0] + ps[2]) - (ps[1] + ps[3]);
    float e8 = (P[0].x - P[0].y) + (P[1].x - P[1].y)
             + (P[2].x - P[2].y) + (P[3].x - P[3].y);
#pragma unroll
    for (int m = 1; m < 16; m <<= 1) {
        e6 += xmove(e6, m); e7 += xmove(e7, m); e8 += xmove(e8, m);
    }
    {
        float h, l;
        swpm(e6, 16, h, l); e6 = h + l;  swpm(e6, 32, h, l); e6 = h + l;
        swpm(e7, 16, h, l); e7 = h + l;  swpm(e7, 32, h, l); e7 = h + l;
        swpm(e8, 16, h, l); e8 = h + l;  swpm(e8, 32, h, l); e8 = h + l;
    }

    float ev[NQ];
#pragma unroll
    for (int w = 0; w < 6; ++w) ev[w] = d[5 - w];
    ev[6] = e6; ev[7] = e7; ev[8] = e8;

    // ---- linear head + log_softmax: lane c (<10) owns class c ----
    float lval = -INFINITY;
    if (lane < NC) {
        float dd = fcbs[lane];
        const float* fw = fcw + lane * NQ;
#pragma unroll
        for (int w = 0; w < NQ; ++w) dd += ev[w] * fw[w];
        lval = dd;
    }
    float mx = lval;
    mx = fmaxf(mx, xmove(mx, 1));
    mx = fmaxf(mx, xmove(mx, 2));
    mx = fmaxf(mx, xmove(mx, 4));
    mx = fmaxf(mx, xmove(mx, 8));
    float e = (lane < NC) ? expf(lval - mx) : 0.f;
    float se = e;
    se += xmove(se, 1); se += xmove(se, 2); se += xmove(se, 4); se += xmove(se, 8);
    if (lane < NC) out[b * NC + lane] = lval - mx - logf(se);
}

extern "C" void kernel_launch(void* const* d_in, const int* in_sizes, int n_in,
                              void* d_out, int out_size, void* d_ws, size_t ws_size,
                              hipStream_t stream) {
    const float* x     = (const float*)d_in[0];
    const float* rot_w = (const float*)d_in[1];
    const float* crx_w = (const float*)d_in[2];
    const float* fc_w  = (const float*)d_in[3];
    const float* fc_b  = (const float*)d_in[4];
    float* out = (float*)d_out;
    const int B = in_sizes[0] / NQ;
    const int blocks = (B + 3) / 4;
    qmlp_kernel<<<blocks, 256, 0, stream>>>(x, rot_w, crx_w, fc_w, fc_b, out, B);
}

// Round 8
// 39.219 us; speedup vs baseline: 1.1323x; 1.1323x over previous
//
#include <hip/hip_runtime.h>
#include <math.h>

#define NQ 9
#define NL 5
#define NC 10

typedef float v2f __attribute__((ext_vector_type(2)));
typedef float v4f __attribute__((ext_vector_type(4)));

__device__ __forceinline__ v2f sp(float x) { v2f r; r.x = x; r.y = x; return r; }

// ---- gfx950 permlane pair swap (ONE VALU instr, no copies): (a,b) -> (S0,S1)
// mask32: S0[i] = i<32 ? a[i] : b[i-32]   (all bit5=0-side values)
//         S1[i] = i<32 ? a[i+32] : b[i]   (all bit5=1-side values)
// mask16: same within each 32-lane half on bit4. Self-inverse.
__device__ __forceinline__ void plswap(float& a, float& b, int mask) {
    if (mask == 32) {
        auto r = __builtin_amdgcn_permlane32_swap(__float_as_int(a), __float_as_int(b), false, false);
        a = __int_as_float(r[0]); b = __int_as_float(r[1]);
    } else {
        auto r = __builtin_amdgcn_permlane16_swap(__float_as_int(a), __float_as_int(b), false, false);
        a = __int_as_float(r[0]); b = __int_as_float(r[1]);
    }
}
__device__ __forceinline__ void plswap2(v2f& a, v2f& b, int mask) {
    float ax = a.x, bx = b.x, ay = a.y, by = b.y;
    plswap(ax, bx, mask); plswap(ay, by, mask);
    a.x = ax; a.y = ay; b.x = bx; b.y = by;
}
// Full-state transform into/out of "split space" for lane-mask M (pairs (0,1),(2,3)):
// after this, register pair axis == wire bit M; apply pair-axis gate; call again to restore.
__device__ __forceinline__ void state_swap(v2f (&xr)[4], v2f (&xi)[4], int mask) {
    plswap2(xr[0], xr[1], mask); plswap2(xr[2], xr[3], mask);
    plswap2(xi[0], xi[1], mask); plswap2(xi[2], xi[3], mask);
}

// ---- broadcast-form swpm (epilogue reductions only): x to both operands ->
// r[0]=lo-broadcast, r[1]=hi-broadcast (verified round 7).
__device__ __forceinline__ void swpm(float x, int mask, float& hi, float& lo) {
    if (mask == 32) {
        auto r = __builtin_amdgcn_permlane32_swap(__float_as_int(x), __float_as_int(x), false, false);
        lo = __int_as_float(r[0]); hi = __int_as_float(r[1]);
    } else {
        auto r = __builtin_amdgcn_permlane16_swap(__float_as_int(x), __float_as_int(x), false, false);
        lo = __int_as_float(r[0]); hi = __int_as_float(r[1]);
    }
}

// XOR-lane exchange for masks 1,2,4,8 — DPP only (VALU, 1-2 ops).
__device__ __forceinline__ float xmove(float x, int mask) {
    if (mask == 1)
        return __int_as_float(__builtin_amdgcn_update_dpp(0, __float_as_int(x), 0xB1, 0xF, 0xF, true));
    if (mask == 2)
        return __int_as_float(__builtin_amdgcn_update_dpp(0, __float_as_int(x), 0x4E, 0xF, 0xF, true));
    if (mask == 4) {
        int t = __builtin_amdgcn_update_dpp(0, __float_as_int(x), 0x104, 0xF, 0x5, false); // row_shl:4 banks 0,2
        t = __builtin_amdgcn_update_dpp(t, __float_as_int(x), 0x114, 0xF, 0xA, false);     // row_shr:4 banks 1,3
        return __int_as_float(t);
    }
    return __int_as_float(__builtin_amdgcn_update_dpp(0, __float_as_int(x), 0x128, 0xF, 0xF, true)); // row_ror:8
}
__device__ __forceinline__ v2f xmv2(v2f v, int mask) {
    v2f r; r.x = xmove(v.x, mask); r.y = xmove(v.y, mask); return r;
}

// State packing: lane owns 8 amps as 4 x float2; amp = (j<<1)|comp.
// wire w -> bit 8-w: wires 0..5 -> lane bits 5..0; wire6 -> j bit1; wire7 -> j bit0; wire8 -> comp.

// U = Rot*RX entries from m[8] = {m00r,m00i,m01r,m01i,m10r,m10i,m11r,m11i}
#define FUSED_U(A, Bq, c, s)                                          \
    float u00r = A.x*c + s*A.w,  u00i = A.y*c - s*A.z;                \
    float u01r = A.z*c + s*A.y,  u01i = A.w*c - s*A.x;                \
    float u10r = Bq.x*c + s*Bq.w, u10i = Bq.y*c - s*Bq.z;             \
    float u11r = Bq.z*c + s*Bq.y, u11i = Bq.w*c - s*Bq.x;

// ---- 2x2 complex U across the pair axis (0,1),(2,3) with uniform coefficients.
// Serves: wire7 gate (normal space) AND wire0/wire1 gates (split space).
__device__ __forceinline__ void rot_pair_gate(v2f (&xr)[4], v2f (&xi)[4],
                                              const float* __restrict__ m,
                                              float c, float s) {
    const v4f A = *(const v4f*)m; const v4f Bq = *(const v4f*)(m + 4);
    FUSED_U(A, Bq, c, s)
#pragma unroll
    for (int p = 0; p < 4; p += 2) {
        const int j1 = p + 1;
        v2f a0r = xr[p], a0i = xi[p], a1r = xr[j1], a1i = xi[j1];
        xr[p]  = sp(u00r)*a0r - sp(u00i)*a0i + sp(u01r)*a1r - sp(u01i)*a1i;
        xi[p]  = sp(u00r)*a0i + sp(u00i)*a0r + sp(u01r)*a1i + sp(u01i)*a1r;
        xr[j1] = sp(u10r)*a0r - sp(u10i)*a0i + sp(u11r)*a1r - sp(u11i)*a1i;
        xi[j1] = sp(u10r)*a0i + sp(u10i)*a0r + sp(u11r)*a1i + sp(u11i)*a1r;
    }
}

// ---- CRX (RX on pair axis (0,1),(2,3)), scalar ce/se (ctrl folded by caller) ----
__device__ __forceinline__ void crx_pair_s(v2f (&xr)[4], v2f (&xi)[4], float ce, float se) {
#pragma unroll
    for (int p = 0; p < 4; p += 2) {
        const int j1 = p + 1;
        v2f a0r = xr[p], a0i = xi[p], a1r = xr[j1], a1i = xi[j1];
        xr[p]  = sp(ce)*a0r + sp(se)*a1i;
        xi[p]  = sp(ce)*a0i - sp(se)*a1r;
        xr[j1] = sp(ce)*a1r + sp(se)*a0i;
        xi[j1] = sp(ce)*a1i - sp(se)*a0r;
    }
}
// ---- CRX on pair axis, ctrl = component (packed coefficient) ----
__device__ __forceinline__ void crx_pair_c(v2f (&xr)[4], v2f (&xi)[4], float c, float s) {
    const v2f cev = {1.f, c};
    const v2f sev = {0.f, s};
#pragma unroll
    for (int p = 0; p < 4; p += 2) {
        const int j1 = p + 1;
        v2f a0r = xr[p], a0i = xi[p], a1r = xr[j1], a1i = xi[j1];
        xr[p]  = cev*a0r + sev*a1i;
        xi[p]  = cev*a0i - sev*a1r;
        xr[j1] = cev*a1r + sev*a0i;
        xi[j1] = cev*a1i - sev*a0r;
    }
}

// ---- fused (Rot*RX) on lane bit LB in {0..3}: DPP self/partner form ----
template<int LB>
__device__ __forceinline__ void fused_cross_dpp(v2f (&xr)[4], v2f (&xi)[4],
                                                const float* __restrict__ m,
                                                float c, float s, int lane) {
    const v4f A = *(const v4f*)m; const v4f Bq = *(const v4f*)(m + 4);
    FUSED_U(A, Bq, c, s)
    const int bit = (lane >> LB) & 1;
    const float Csr = bit ? u11r : u00r, Csi = bit ? u11i : u00i;  // self
    const float Cpr = bit ? u10r : u01r, Cpi = bit ? u10i : u01i;  // partner
#pragma unroll
    for (int j = 0; j < 4; ++j) {
        v2f pr = xmv2(xr[j], 1 << LB);
        v2f pi = xmv2(xi[j], 1 << LB);
        v2f ar = xr[j], ai = xi[j];
        xr[j] = sp(Csr)*ar - sp(Csi)*ai + sp(Cpr)*pr - sp(Cpi)*pi;
        xi[j] = sp(Csr)*ai + sp(Csi)*ar + sp(Cpr)*pi + sp(Cpi)*pr;
    }
}

// ---- fused (Rot*RX) on j bit1 (wire 6): pairs (0,2),(1,3) ----
__device__ __forceinline__ void fused_local_j1(v2f (&xr)[4], v2f (&xi)[4],
                                               const float* __restrict__ m,
                                               float c, float s) {
    const v4f A = *(const v4f*)m; const v4f Bq = *(const v4f*)(m + 4);
    FUSED_U(A, Bq, c, s)
#pragma unroll
    for (int j = 0; j < 2; ++j) {
        const int j1 = j | 2;
        v2f a0r = xr[j], a0i = xi[j], a1r = xr[j1], a1i = xi[j1];
        xr[j]  = sp(u00r)*a0r - sp(u00i)*a0i + sp(u01r)*a1r - sp(u01i)*a1i;
        xi[j]  = sp(u00r)*a0i + sp(u00i)*a0r + sp(u01r)*a1i + sp(u01i)*a1r;
        xr[j1] = sp(u10r)*a0r - sp(u10i)*a0i + sp(u11r)*a1r - sp(u11i)*a1i;
        xi[j1] = sp(u10r)*a0i + sp(u10i)*a0r + sp(u11r)*a1i + sp(u11i)*a1r;
    }
}

// ---- fused (Rot*RX) on the component bit (wire 8): broadcast form ----
__device__ __forceinline__ void fused_local_c(v2f (&xr)[4], v2f (&xi)[4],
                                              const float* __restrict__ m,
                                              float c, float s) {
    const v4f A = *(const v4f*)m; const v4f Bq = *(const v4f*)(m + 4);
    v2f U0r = { A.x*c + s*A.w,  Bq.x*c + s*Bq.w };
    v2f U0i = { A.y*c - s*A.z,  Bq.y*c - s*Bq.z };
    v2f U1r = { A.z*c + s*A.y,  Bq.z*c + s*Bq.y };
    v2f U1i = { A.w*c - s*A.x,  Bq.w*c - s*Bq.x };
#pragma unroll
    for (int j = 0; j < 4; ++j) {
        v2f A0r = xr[j].xx, A0i = xi[j].xx, A1r = xr[j].yy, A1i = xi[j].yy;
        xr[j] = U0r*A0r - U0i*A0i + U1r*A1r - U1i*A1i;
        xi[j] = U0r*A0i + U0i*A0r + U1r*A1i + U1i*A1r;
    }
}

// ---- CRX: ctrl lane bit CB, tgt lane-mask M in {1,2,4,8}: DPP ----
template<int CB, int M>
__device__ __forceinline__ void crx_dpp(v2f (&xr)[4], v2f (&xi)[4], float c, float s, int lane) {
    const bool ctrl = (lane >> CB) & 1;
    const float ce = ctrl ? c : 1.f;
    const float se = ctrl ? s : 0.f;
#pragma unroll
    for (int j = 0; j < 4; ++j) {
        v2f pr = xmv2(xr[j], M);
        v2f pi = xmv2(xi[j], M);
        xr[j] = sp(ce)*xr[j] + sp(se)*pi;
        xi[j] = sp(ce)*xi[j] - sp(se)*pr;
    }
}

// ---- CRX w=5: ctrl lane bit0 (wire5), tgt j bit1 (wire6): pairs (0,2),(1,3) ----
__device__ __forceinline__ void crx_l_j1(v2f (&xr)[4], v2f (&xi)[4], float c, float s, int lane) {
    const bool ctrl = lane & 1;
    const float ce = ctrl ? c : 1.f;
    const float se = ctrl ? s : 0.f;
#pragma unroll
    for (int j = 0; j < 2; ++j) {
        const int j1 = j | 2;
        v2f a0r = xr[j], a0i = xi[j], a1r = xr[j1], a1i = xi[j1];
        xr[j]  = sp(ce)*a0r + sp(se)*a1i;
        xi[j]  = sp(ce)*a0i - sp(se)*a1r;
        xr[j1] = sp(ce)*a1r + sp(se)*a0i;
        xi[j1] = sp(ce)*a1i - sp(se)*a0r;
    }
}

// ---- CRX w=6: ctrl j bit1, tgt j bit0: pair (2,3) ----
__device__ __forceinline__ void crx_j1_j0(v2f (&xr)[4], v2f (&xi)[4], float c, float s) {
    v2f a0r = xr[2], a0i = xi[2], a1r = xr[3], a1i = xi[3];
    xr[2] = sp(c)*a0r + sp(s)*a1i;
    xi[2] = sp(c)*a0i - sp(s)*a1r;
    xr[3] = sp(c)*a1r + sp(s)*a0i;
    xi[3] = sp(c)*a1i - sp(s)*a0r;
}

// ---- CRX w=7: ctrl j bit0 (j in {1,3}), tgt component ----
__device__ __forceinline__ void crx_j0_c(v2f (&xr)[4], v2f (&xi)[4], float c, float s) {
#pragma unroll
    for (int j = 1; j < 4; j += 2) {
        v2f vr = xr[j], vi = xi[j];
        xr[j] = sp(c)*vr + sp(s)*vi.yx;
        xi[j] = sp(c)*vi - sp(s)*vr.yx;
    }
}

__global__ __launch_bounds__(256) void qmlp_kernel(
    const float* __restrict__ x, const float* __restrict__ rot_w,
    const float* __restrict__ crx_w, const float* __restrict__ fc_w,
    const float* __restrict__ fc_b, float* __restrict__ out, int B)
{
    __shared__ __align__(16) float rotm[NL * NQ * 8];
    __shared__ __align__(16) float crxm[NL * NQ * 2];
    __shared__ float fcw[NC * NQ];
    __shared__ float fcbs[NC];

    const int tid = threadIdx.x;
    if (tid < NL * NQ) {
        const float phi = rot_w[tid * 3 + 0];
        const float th  = rot_w[tid * 3 + 1];
        const float om  = rot_w[tid * 3 + 2];
        float st, ct; sincosf(0.5f * th, &st, &ct);
        float spo, cpo; sincosf(0.5f * (phi + om), &spo, &cpo);
        float smo, cmo; sincosf(0.5f * (phi - om), &smo, &cmo);
        float* m = rotm + tid * 8;
        m[0] =  ct * cpo; m[1] = -ct * spo;
        m[2] = -st * cmo; m[3] = -st * smo;
        m[4] =  st * cmo; m[5] = -st * smo;
        m[6] =  ct * cpo; m[7] =  ct * spo;
        float sc, cc; sincosf(0.5f * crx_w[tid], &sc, &cc);
        crxm[tid * 2 + 0] = cc; crxm[tid * 2 + 1] = sc;
    }
    if (tid < NC * NQ) fcw[tid] = fc_w[tid];
    if (tid < NC) fcbs[tid] = fc_b[tid];
    __syncthreads();

    const int lane = tid & 63;
    const int b = blockIdx.x * 4 + (tid >> 6);
    if (b >= B) return;

    float cx[NQ], sx[NQ];
#pragma unroll
    for (int w = 0; w < NQ; ++w) __sincosf(0.5f * x[b * NQ + w], &sx[w], &cx[w]);

    v2f xr[4], xi[4];

    // ---- Layer 0 single-qubit block on |0..0>: direct product state ----
    {
        const float* M = rotm;
        float ar = 1.f, ai = 0.f;
#pragma unroll
        for (int w = 0; w < 6; ++w) {
            const float* m = M + w * 8;
            float c = cx[w], s = sx[w];
            int bit = (lane >> (5 - w)) & 1;
            float u0r = m[0]*c + s*m[3], u0i = m[1]*c - s*m[2];
            float u1r = m[4]*c + s*m[7], u1i = m[5]*c - s*m[6];
            float vr = bit ? u1r : u0r;
            float vi = bit ? u1i : u0i;
            float nr = ar * vr - ai * vi;
            float ni = ar * vi + ai * vr;
            ar = nr; ai = ni;
        }
        float vr67[2][2], vi67[2][2];
#pragma unroll
        for (int q = 0; q < 2; ++q) {
            const float* m = M + (6 + q) * 8;
            float c = cx[6 + q], s = sx[6 + q];
            vr67[q][0] = m[0]*c + s*m[3]; vi67[q][0] = m[1]*c - s*m[2];
            vr67[q][1] = m[4]*c + s*m[7]; vi67[q][1] = m[5]*c - s*m[6];
        }
        float t6r[2], t6i[2];
#pragma unroll
        for (int bb = 0; bb < 2; ++bb) {
            t6r[bb] = ar * vr67[0][bb] - ai * vi67[0][bb];
            t6i[bb] = ar * vi67[0][bb] + ai * vr67[0][bb];
        }
        float t67r[4], t67i[4];
#pragma unroll
        for (int j = 0; j < 4; ++j) {
            int b6 = j >> 1, b7 = j & 1;
            t67r[j] = t6r[b6] * vr67[1][b7] - t6i[b6] * vi67[1][b7];
            t67i[j] = t6r[b6] * vi67[1][b7] + t6i[b6] * vr67[1][b7];
        }
        const float* m8 = M + 8 * 8;
        float c8 = cx[8], s8 = sx[8];
        v2f V8r = { m8[0]*c8 + s8*m8[3], m8[4]*c8 + s8*m8[7] };
        v2f V8i = { m8[1]*c8 - s8*m8[2], m8[5]*c8 - s8*m8[6] };
#pragma unroll
        for (int j = 0; j < 4; ++j) {
            xr[j] = sp(t67r[j])*V8r - sp(t67i[j])*V8i;
            xi[j] = sp(t67r[j])*V8i + sp(t67i[j])*V8r;
        }
    }

    // ---- Layer 0 CRX ring ----
    {
        const float* C = crxm;
        // w=0 (ctrl wire0=bit5, tgt wire1=bit4) in mask-16 split space
        state_swap(xr, xi, 16);
        {
            const bool ctrl = (lane >> 5) & 1;
            crx_pair_s(xr, xi, ctrl ? C[0] : 1.f, ctrl ? C[1] : 0.f);
        }
        state_swap(xr, xi, 16);
        crx_dpp<4, 8>(xr, xi, C[2],  C[3],  lane);  // w=1
        crx_dpp<3, 4>(xr, xi, C[4],  C[5],  lane);  // w=2
        crx_dpp<2, 2>(xr, xi, C[6],  C[7],  lane);  // w=3
        crx_dpp<1, 1>(xr, xi, C[8],  C[9],  lane);  // w=4
        crx_l_j1     (xr, xi, C[10], C[11], lane);  // w=5
        crx_j1_j0    (xr, xi, C[12], C[13]);        // w=6
        crx_j0_c     (xr, xi, C[14], C[15]);        // w=7
        // w=8 (ctrl wire8=comp, tgt wire0=bit5) in mask-32 split space — STAY swapped
        state_swap(xr, xi, 32);
        crx_pair_c(xr, xi, C[16], C[17]);
    }

    // ---- Layers 1..4 (enter each layer in mask-32 split space) ----
    for (int n = 1; n < NL; ++n) {
        const float* M = rotm + n * NQ * 8;
        const float* C = crxm + n * NQ * 2;
        // wire0 gate while still in mask-32 space (uniform pair gate), then restore
        rot_pair_gate(xr, xi, M + 0 * 8, cx[0], sx[0]);
        state_swap(xr, xi, 32);
        // wires 2..5 (DPP cross), 6..8 (local) — all commute, any order
        fused_cross_dpp<3>(xr, xi, M + 2 * 8, cx[2], sx[2], lane);
        fused_cross_dpp<2>(xr, xi, M + 3 * 8, cx[3], sx[3], lane);
        fused_cross_dpp<1>(xr, xi, M + 4 * 8, cx[4], sx[4], lane);
        fused_cross_dpp<0>(xr, xi, M + 5 * 8, cx[5], sx[5], lane);
        fused_local_j1(xr, xi, M + 6 * 8, cx[6], sx[6]);           // wire6
        rot_pair_gate (xr, xi, M + 7 * 8, cx[7], sx[7]);           // wire7 (pair axis)
        fused_local_c (xr, xi, M + 8 * 8, cx[8], sx[8]);           // wire8
        // wire1 gate + CRX w=0 share one mask-16 split-space session
        state_swap(xr, xi, 16);
        rot_pair_gate(xr, xi, M + 1 * 8, cx[1], sx[1]);            // wire1
        {
            const bool ctrl = (lane >> 5) & 1;                     // wire0 ctrl (bit5 preserved)
            crx_pair_s(xr, xi, ctrl ? C[0] : 1.f, ctrl ? C[1] : 0.f);  // w=0
        }
        state_swap(xr, xi, 16);
        crx_dpp<4, 8>(xr, xi, C[2],  C[3],  lane);  // w=1
        crx_dpp<3, 4>(xr, xi, C[4],  C[5],  lane);  // w=2
        crx_dpp<2, 2>(xr, xi, C[6],  C[7],  lane);  // w=3
        crx_dpp<1, 1>(xr, xi, C[8],  C[9],  lane);  // w=4
        crx_l_j1     (xr, xi, C[10], C[11], lane);  // w=5
        crx_j1_j0    (xr, xi, C[12], C[13]);        // w=6
        crx_j0_c     (xr, xi, C[14], C[15]);        // w=7
        state_swap(xr, xi, 32);
        crx_pair_c(xr, xi, C[16], C[17]);           // w=8 — STAY swapped for next layer
    }
    state_swap(xr, xi, 32);  // restore to normal space for the epilogue

    // ---- probabilities and <Z_w> ----
    v2f P[4];
#pragma unroll
    for (int j = 0; j < 4; ++j) P[j] = xr[j]*xr[j] + xi[j]*xi[j];
    float ps[4];
#pragma unroll
    for (int j = 0; j < 4; ++j) ps[j] = P[j].x + P[j].y;
    float psum = ps[0] + ps[1] + ps[2] + ps[3];

    // lane-bit <Z>'s: shared-prefix signed reduction; masks 16/32 via permlane pair
    float t = psum;
    float d[6];
#pragma unroll
    for (int bb = 0; bb < 6; ++bb) {
        if (bb < 4) {
#pragma unroll
            for (int jj = 0; jj < 6; ++jj)
                if (jj < bb) d[jj] += xmove(d[jj], 1 << bb);
            float o = xmove(t, 1 << bb);
            d[bb] = ((lane >> bb) & 1) ? (o - t) : (t - o);
            t += o;
        } else {
#pragma unroll
            for (int jj = 0; jj < 6; ++jj)
                if (jj < bb) { float h, l; swpm(d[jj], 1 << bb, h, l); d[jj] = h + l; }
            float h, l; swpm(t, 1 << bb, h, l);
            d[bb] = l - h;    // sum(bit=0 half) - sum(bit=1 half), valid in all lanes
            t = h + l;
        }
    }
    // local-bit <Z>'s
    float e6 = (ps[0] + ps[1]) - (ps[2] + ps[3]);
    float e7 = (ps[0] + ps[2]) - (ps[1] + ps[3]);
    float e8 = (P[0].x - P[0].y) + (P[1].x - P[1].y)
             + (P[2].x - P[2].y) + (P[3].x - P[3].y);
#pragma unroll
    for (int m = 1; m < 16; m <<= 1) {
        e6 += xmove(e6, m); e7 += xmove(e7, m); e8 += xmove(e8, m);
    }
    {
        float h, l;
        swpm(e6, 16, h, l); e6 = h + l;  swpm(e6, 32, h, l); e6 = h + l;
        swpm(e7, 16, h, l); e7 = h + l;  swpm(e7, 32, h, l); e7 = h + l;
        swpm(e8, 16, h, l); e8 = h + l;  swpm(e8, 32, h, l); e8 = h + l;
    }

    float ev[NQ];
#pragma unroll
    for (int w = 0; w < 6; ++w) ev[w] = d[5 - w];
    ev[6] = e6; ev[7] = e7; ev[8] = e8;

    // ---- linear head + log_softmax: lane c (<10) owns class c ----
    float lval = -INFINITY;
    if (lane < NC) {
        float dd = fcbs[lane];
        const float* fw = fcw + lane * NQ;
#pragma unroll
        for (int w = 0; w < NQ; ++w) dd += ev[w] * fw[w];
        lval = dd;
    }
    float mx = lval;
    mx = fmaxf(mx, xmove(mx, 1));
    mx = fmaxf(mx, xmove(mx, 2));
    mx = fmaxf(mx, xmove(mx, 4));
    mx = fmaxf(mx, xmove(mx, 8));
    float e = (lane < NC) ? expf(lval - mx) : 0.f;
    float se = e;
    se += xmove(se, 1); se += xmove(se, 2); se += xmove(se, 4); se += xmove(se, 8);
    if (lane < NC) out[b * NC + lane] = lval - mx - logf(se);
}

extern "C" void kernel_launch(void* const* d_in, const int* in_sizes, int n_in,
                              void* d_out, int out_size, void* d_ws, size_t ws_size,
                              hipStream_t stream) {
    const float* x     = (const float*)d_in[0];
    const float* rot_w = (const float*)d_in[1];
    const float* crx_w = (const float*)d_in[2];
    const float* fc_w  = (const float*)d_in[3];
    const float* fc_b  = (const float*)d_in[4];
    float* out = (float*)d_out;
    const int B = in_sizes[0] / NQ;
    const int blocks = (B + 3) / 4;
    qmlp_kernel<<<blocks, 256, 0, stream>>>(x, rot_w, crx_w, fc_w, fc_b, out, B);
}

// Round 9
// 31.061 us; speedup vs baseline: 1.4296x; 1.2626x over previous
//
#include <hip/hip_runtime.h>
#include <math.h>

#define NQ 9
#define NL 5
#define NC 10

typedef float v2f __attribute__((ext_vector_type(2)));
typedef float v4f __attribute__((ext_vector_type(4)));

__device__ __forceinline__ v2f sp(float x) { v2f r; r.x = x; r.y = x; return r; }

// ---- gfx950 permlane pair swap: (a,b) -> (S0 = bitM=0 side, S1 = bitM=1 side) ----
__device__ __forceinline__ void plswap(float& a, float& b, int mask) {
    if (mask == 32) {
        auto r = __builtin_amdgcn_permlane32_swap(__float_as_int(a), __float_as_int(b), false, false);
        a = __int_as_float(r[0]); b = __int_as_float(r[1]);
    } else {
        auto r = __builtin_amdgcn_permlane16_swap(__float_as_int(a), __float_as_int(b), false, false);
        a = __int_as_float(r[0]); b = __int_as_float(r[1]);
    }
}
__device__ __forceinline__ void plswap2(v2f& a, v2f& b, int mask) {
    float ax = a.x, bx = b.x, ay = a.y, by = b.y;
    plswap(ax, bx, mask); plswap(ay, by, mask);
    a.x = ax; a.y = ay; b.x = bx; b.y = by;
}
__device__ __forceinline__ void state_swap(v2f (&xr)[4], v2f (&xi)[4], int mask) {
    plswap2(xr[0], xr[1], mask); plswap2(xr[2], xr[3], mask);
    plswap2(xi[0], xi[1], mask); plswap2(xi[2], xi[3], mask);
}

// ---- broadcast swpm (epilogue only): r[0]=lo-broadcast, r[1]=hi-broadcast ----
__device__ __forceinline__ void swpm(float x, int mask, float& hi, float& lo) {
    if (mask == 32) {
        auto r = __builtin_amdgcn_permlane32_swap(__float_as_int(x), __float_as_int(x), false, false);
        lo = __int_as_float(r[0]); hi = __int_as_float(r[1]);
    } else {
        auto r = __builtin_amdgcn_permlane16_swap(__float_as_int(x), __float_as_int(x), false, false);
        lo = __int_as_float(r[0]); hi = __int_as_float(r[1]);
    }
}

// XOR-lane exchange masks 1,2,4,8 — DPP (VALU, 1-2 ops).
__device__ __forceinline__ float xmove(float x, int mask) {
    if (mask == 1)
        return __int_as_float(__builtin_amdgcn_update_dpp(0, __float_as_int(x), 0xB1, 0xF, 0xF, true));
    if (mask == 2)
        return __int_as_float(__builtin_amdgcn_update_dpp(0, __float_as_int(x), 0x4E, 0xF, 0xF, true));
    if (mask == 4) {
        int t = __builtin_amdgcn_update_dpp(0, __float_as_int(x), 0x104, 0xF, 0x5, false);
        t = __builtin_amdgcn_update_dpp(t, __float_as_int(x), 0x114, 0xF, 0xA, false);
        return __int_as_float(t);
    }
    return __int_as_float(__builtin_amdgcn_update_dpp(0, __float_as_int(x), 0x128, 0xF, 0xF, true));
}
__device__ __forceinline__ v2f xmv2(v2f v, int mask) {
    v2f r; r.x = xmove(v.x, mask); r.y = xmove(v.y, mask); return r;
}

// State packing: lane owns 8 amps as 4 x float2; amp = (j<<1)|comp.
// wire w -> bit 8-w: wires 0..5 -> lane bits 5..0; wire6 -> j bit1; wire7 -> j bit0; wire8 -> comp.

// SU(2): every gate matrix M (Rot, RX(t)*Rot, M*RX) has m11=conj(m00), m10=-conj(m01).
// Tables store only (m00r,m00i,m01r,m01i). U = M*RX(x): only u00,u01 needed (8 FMA):
#define HALF_U(A, c, s)                                               \
    float u00r = A.x*c + s*A.w,  u00i = A.y*c - s*A.z;                \
    float u01r = A.z*c + s*A.y,  u01i = A.w*c - s*A.x;

// ---- uncontrolled fused gate on pair axis (0,1),(2,3) ----
__device__ __forceinline__ void rot_pair(v2f (&xr)[4], v2f (&xi)[4],
                                         const float* __restrict__ m, float c, float s) {
    const v4f A = *(const v4f*)m;
    HALF_U(A, c, s)
#pragma unroll
    for (int p = 0; p < 4; p += 2) {
        const int q = p + 1;
        v2f a0r = xr[p], a0i = xi[p], a1r = xr[q], a1i = xi[q];
        xr[p] = sp(u00r)*a0r - sp(u00i)*a0i + sp(u01r)*a1r - sp(u01i)*a1i;
        xi[p] = sp(u00r)*a0i + sp(u00i)*a0r + sp(u01r)*a1i + sp(u01i)*a1r;
        xr[q] = sp(-u01r)*a0r - sp(u01i)*a0i + sp(u00r)*a1r + sp(u00i)*a1i;   // row1 = (-conj u01, conj u00)
        xi[q] = sp(-u01r)*a0i + sp(u01i)*a0r + sp(u00r)*a1i - sp(u00i)*a1r;
    }
}

// ---- FUSED (CRX(ctrl)·Rot·RX) cross gate: ctrl lane bit CB selects M0/M1; tgt lane bit LB ----
template<int CB, int LB>
__device__ __forceinline__ void fusedC_cross(v2f (&xr)[4], v2f (&xi)[4],
                                             const float* __restrict__ m,
                                             float c, float s, int lane) {
    const v4f A0 = *(const v4f*)m;
    const v4f A1 = *(const v4f*)(m + 4);
    const bool ctrl = (lane >> CB) & 1;
    v4f A;
    A.x = ctrl ? A1.x : A0.x;  A.y = ctrl ? A1.y : A0.y;
    A.z = ctrl ? A1.z : A0.z;  A.w = ctrl ? A1.w : A0.w;
    HALF_U(A, c, s)
    const int bit = (lane >> LB) & 1;
    const float Csr = u00r,  Cpi = u01i;                 // uniform (SU2)
    const float Csi = bit ? -u00i : u00i;
    const float Cpr = bit ? -u01r : u01r;
#pragma unroll
    for (int j = 0; j < 4; ++j) {
        v2f pr = xmv2(xr[j], 1 << LB);
        v2f pi = xmv2(xi[j], 1 << LB);
        v2f ar = xr[j], ai = xi[j];
        xr[j] = sp(Csr)*ar - sp(Csi)*ai + sp(Cpr)*pr - sp(Cpi)*pi;
        xi[j] = sp(Csr)*ai + sp(Csi)*ar + sp(Cpr)*pi + sp(Cpi)*pr;
    }
}

// ---- FUSED gate on j bit1 (wire6), ctrl = lane bit0 (wire5) ----
__device__ __forceinline__ void fusedC_j1(v2f (&xr)[4], v2f (&xi)[4],
                                          const float* __restrict__ m,
                                          float c, float s, int lane) {
    const v4f A0 = *(const v4f*)m;
    const v4f A1 = *(const v4f*)(m + 4);
    const bool ctrl = lane & 1;
    v4f A;
    A.x = ctrl ? A1.x : A0.x;  A.y = ctrl ? A1.y : A0.y;
    A.z = ctrl ? A1.z : A0.z;  A.w = ctrl ? A1.w : A0.w;
    HALF_U(A, c, s)
#pragma unroll
    for (int j = 0; j < 2; ++j) {
        const int q = j | 2;
        v2f a0r = xr[j], a0i = xi[j], a1r = xr[q], a1i = xi[q];
        xr[j] = sp(u00r)*a0r - sp(u00i)*a0i + sp(u01r)*a1r - sp(u01i)*a1i;
        xi[j] = sp(u00r)*a0i + sp(u00i)*a0r + sp(u01r)*a1i + sp(u01i)*a1r;
        xr[q] = sp(-u01r)*a0r - sp(u01i)*a0i + sp(u00r)*a1r + sp(u00i)*a1i;
        xi[q] = sp(-u01r)*a0i + sp(u01i)*a0r + sp(u00r)*a1i - sp(u00i)*a1r;
    }
}

// ---- uncontrolled fused gate on component bit (wire 8): broadcast form ----
__device__ __forceinline__ void rot_comp(v2f (&xr)[4], v2f (&xi)[4],
                                         const float* __restrict__ m, float c, float s) {
    const v4f A = *(const v4f*)m;
    HALF_U(A, c, s)
    v2f U0r = { u00r, -u01r }, U0i = { u00i,  u01i };
    v2f U1r = { u01r,  u00r }, U1i = { u01i, -u00i };
#pragma unroll
    for (int j = 0; j < 4; ++j) {
        v2f A0r = xr[j].xx, A0i = xi[j].xx, A1r = xr[j].yy, A1i = xi[j].yy;
        xr[j] = U0r*A0r - U0i*A0i + U1r*A1r - U1i*A1i;
        xi[j] = U0r*A0i + U0i*A0r + U1r*A1i + U1i*A1r;
    }
}

// ---- CRX helpers (layer 0 ring + unfused C01/C67/C78/C80) ----
template<int CB, int M>
__device__ __forceinline__ void crx_dpp(v2f (&xr)[4], v2f (&xi)[4], float c, float s, int lane) {
    const bool ctrl = (lane >> CB) & 1;
    const float ce = ctrl ? c : 1.f;
    const float se = ctrl ? s : 0.f;
#pragma unroll
    for (int j = 0; j < 4; ++j) {
        v2f pr = xmv2(xr[j], M);
        v2f pi = xmv2(xi[j], M);
        xr[j] = sp(ce)*xr[j] + sp(se)*pi;
        xi[j] = sp(ce)*xi[j] - sp(se)*pr;
    }
}
__device__ __forceinline__ void crx_pair_s(v2f (&xr)[4], v2f (&xi)[4], float ce, float se) {
#pragma unroll
    for (int p = 0; p < 4; p += 2) {
        const int q = p + 1;
        v2f a0r = xr[p], a0i = xi[p], a1r = xr[q], a1i = xi[q];
        xr[p] = sp(ce)*a0r + sp(se)*a1i;
        xi[p] = sp(ce)*a0i - sp(se)*a1r;
        xr[q] = sp(ce)*a1r + sp(se)*a0i;
        xi[q] = sp(ce)*a1i - sp(se)*a0r;
    }
}
__device__ __forceinline__ void crx_pair_c(v2f (&xr)[4], v2f (&xi)[4], float c, float s) {
    const v2f cev = {1.f, c};
    const v2f sev = {0.f, s};
#pragma unroll
    for (int p = 0; p < 4; p += 2) {
        const int q = p + 1;
        v2f a0r = xr[p], a0i = xi[p], a1r = xr[q], a1i = xi[q];
        xr[p] = cev*a0r + sev*a1i;
        xi[p] = cev*a0i - sev*a1r;
        xr[q] = cev*a1r + sev*a0i;
        xi[q] = cev*a1i - sev*a0r;
    }
}
__device__ __forceinline__ void crx_l_j1(v2f (&xr)[4], v2f (&xi)[4], float c, float s, int lane) {
    const bool ctrl = lane & 1;
    const float ce = ctrl ? c : 1.f;
    const float se = ctrl ? s : 0.f;
#pragma unroll
    for (int j = 0; j < 2; ++j) {
        const int q = j | 2;
        v2f a0r = xr[j], a0i = xi[j], a1r = xr[q], a1i = xi[q];
        xr[j] = sp(ce)*a0r + sp(se)*a1i;
        xi[j] = sp(ce)*a0i - sp(se)*a1r;
        xr[q] = sp(ce)*a1r + sp(se)*a0i;
        xi[q] = sp(ce)*a1i - sp(se)*a0r;
    }
}
__device__ __forceinline__ void crx_j1_j0(v2f (&xr)[4], v2f (&xi)[4], float c, float s) {
    v2f a0r = xr[2], a0i = xi[2], a1r = xr[3], a1i = xi[3];
    xr[2] = sp(c)*a0r + sp(s)*a1i;
    xi[2] = sp(c)*a0i - sp(s)*a1r;
    xr[3] = sp(c)*a1r + sp(s)*a0i;
    xi[3] = sp(c)*a1i - sp(s)*a0r;
}
__device__ __forceinline__ void crx_j0_c(v2f (&xr)[4], v2f (&xi)[4], float c, float s) {
#pragma unroll
    for (int j = 1; j < 4; j += 2) {
        v2f vr = xr[j], vi = xi[j];
        xr[j] = sp(c)*vr + sp(s)*vi.yx;
        xi[j] = sp(c)*vi - sp(s)*vr.yx;
    }
}

__global__ __launch_bounds__(256) void qmlp_kernel(
    const float* __restrict__ x, const float* __restrict__ rot_w,
    const float* __restrict__ crx_w, const float* __restrict__ fc_w,
    const float* __restrict__ fc_b, float* __restrict__ out, int B)
{
    // per (n,w): [0..3] = M0 (m00,m01), [4..7] = M1 = RX(theta_{w-1}) * M0  (m00,m01)
    __shared__ __align__(16) float rotm[NL * NQ * 8];
    __shared__ __align__(16) float crxm[NL * NQ * 2];
    __shared__ float fcw[NC * NQ];
    __shared__ float fcbs[NC];

    const int tid = threadIdx.x;
    if (tid < NL * NQ) {
        const int n = tid / NQ, w = tid % NQ;
        const float phi = rot_w[tid * 3 + 0];
        const float th  = rot_w[tid * 3 + 1];
        const float om  = rot_w[tid * 3 + 2];
        float st, ct; sincosf(0.5f * th, &st, &ct);
        float spo, cpo; sincosf(0.5f * (phi + om), &spo, &cpo);
        float smo, cmo; sincosf(0.5f * (phi - om), &smo, &cmo);
        const float m00r =  ct * cpo, m00i = -ct * spo;
        const float m01r = -st * cmo, m01i = -st * smo;
        float* m = rotm + tid * 8;
        m[0] = m00r; m[1] = m00i; m[2] = m01r; m[3] = m01i;
        // M1 = RX(theta of CRX with ctrl w-1) * M0   (SU2: needs only m00,m01)
        const int nb = n * NQ + (w + NQ - 1) % NQ;
        float sq, cq; sincosf(0.5f * crx_w[nb], &sq, &cq);
        m[4] = cq*m00r + sq*m01i;
        m[5] = cq*m00i + sq*m01r;
        m[6] = cq*m01r - sq*m00i;
        m[7] = cq*m01i - sq*m00r;
        float sc, cc; sincosf(0.5f * crx_w[tid], &sc, &cc);
        crxm[tid * 2 + 0] = cc; crxm[tid * 2 + 1] = sc;
    }
    if (tid < NC * NQ) fcw[tid] = fc_w[tid];
    if (tid < NC) fcbs[tid] = fc_b[tid];
    __syncthreads();

    const int lane = tid & 63;
    const int b = blockIdx.x * 4 + (tid >> 6);
    if (b >= B) return;

    float cx[NQ], sx[NQ];
#pragma unroll
    for (int w = 0; w < NQ; ++w) __sincosf(0.5f * x[b * NQ + w], &sx[w], &cx[w]);

    v2f xr[4], xi[4];

    // ---- Layer 0 single-qubit block on |0..0>: direct product state (SU2 columns) ----
    {
        const float* M = rotm;
        float ar = 1.f, ai = 0.f;
#pragma unroll
        for (int w = 0; w < 6; ++w) {
            const v4f A = *(const v4f*)(M + w * 8);
            float c = cx[w], s = sx[w];
            HALF_U(A, c, s)
            int bit = (lane >> (5 - w)) & 1;
            float vr = bit ? -u01r : u00r;      // col0 = (u00, -conj u01)
            float vi = bit ?  u01i : u00i;
            float nr = ar * vr - ai * vi;
            float ni = ar * vi + ai * vr;
            ar = nr; ai = ni;
        }
        float vr67[2][2], vi67[2][2];
#pragma unroll
        for (int q = 0; q < 2; ++q) {
            const v4f A = *(const v4f*)(M + (6 + q) * 8);
            float c = cx[6 + q], s = sx[6 + q];
            HALF_U(A, c, s)
            vr67[q][0] = u00r;  vi67[q][0] = u00i;
            vr67[q][1] = -u01r; vi67[q][1] = u01i;
        }
        float t6r[2], t6i[2];
#pragma unroll
        for (int bb = 0; bb < 2; ++bb) {
            t6r[bb] = ar * vr67[0][bb] - ai * vi67[0][bb];
            t6i[bb] = ar * vi67[0][bb] + ai * vr67[0][bb];
        }
        float t67r[4], t67i[4];
#pragma unroll
        for (int j = 0; j < 4; ++j) {
            int b6 = j >> 1, b7 = j & 1;
            t67r[j] = t6r[b6] * vr67[1][b7] - t6i[b6] * vi67[1][b7];
            t67i[j] = t6r[b6] * vi67[1][b7] + t6i[b6] * vr67[1][b7];
        }
        {
            const v4f A = *(const v4f*)(M + 8 * 8);
            float c = cx[8], s = sx[8];
            HALF_U(A, c, s)
            v2f V8r = { u00r, -u01r };
            v2f V8i = { u00i,  u01i };
#pragma unroll
            for (int j = 0; j < 4; ++j) {
                xr[j] = sp(t67r[j])*V8r - sp(t67i[j])*V8i;
                xi[j] = sp(t67r[j])*V8i + sp(t67i[j])*V8r;
            }
        }
    }

    // ---- Layer 0 CRX ring (C01..C80) ----
    {
        const float* C = crxm;
        state_swap(xr, xi, 16);
        {
            const bool ctrl = (lane >> 5) & 1;
            crx_pair_s(xr, xi, ctrl ? C[0] : 1.f, ctrl ? C[1] : 0.f);   // C01
        }
        state_swap(xr, xi, 16);
        crx_dpp<4, 8>(xr, xi, C[2],  C[3],  lane);  // C12
        crx_dpp<3, 4>(xr, xi, C[4],  C[5],  lane);  // C23
        crx_dpp<2, 2>(xr, xi, C[6],  C[7],  lane);  // C34
        crx_dpp<1, 1>(xr, xi, C[8],  C[9],  lane);  // C45
        crx_l_j1     (xr, xi, C[10], C[11], lane);  // C56
        crx_j1_j0    (xr, xi, C[12], C[13]);        // C67
        crx_j0_c     (xr, xi, C[14], C[15]);        // C78
        state_swap(xr, xi, 32);
        crx_pair_c(xr, xi, C[16], C[17]);           // C80 — stay in split-32 space
    }

    // ---- Layers 1..4: ring-ordered, CRX fused into wire gates ----
    for (int n = 1; n < NL; ++n) {
        const float* M = rotm + n * NQ * 8;
        const float* C = crxm + n * NQ * 2;
        rot_pair(xr, xi, M + 0 * 8, cx[0], sx[0]);              // G0 (pair axis = wire0, split-32)
        state_swap(xr, xi, 32);
        state_swap(xr, xi, 16);
        rot_pair(xr, xi, M + 1 * 8, cx[1], sx[1]);              // G1 (pair axis = wire1)
        {
            const bool ctrl = (lane >> 5) & 1;
            crx_pair_s(xr, xi, ctrl ? C[0] : 1.f, ctrl ? C[1] : 0.f);  // C01
        }
        state_swap(xr, xi, 16);
        fusedC_cross<4, 3>(xr, xi, M + 2 * 8, cx[2], sx[2], lane);  // G2·C12
        fusedC_cross<3, 2>(xr, xi, M + 3 * 8, cx[3], sx[3], lane);  // G3·C23
        fusedC_cross<2, 1>(xr, xi, M + 4 * 8, cx[4], sx[4], lane);  // G4·C34
        fusedC_cross<1, 0>(xr, xi, M + 5 * 8, cx[5], sx[5], lane);  // G5·C45
        fusedC_j1(xr, xi, M + 6 * 8, cx[6], sx[6], lane);           // G6·C56
        rot_pair(xr, xi, M + 7 * 8, cx[7], sx[7]);                  // G7 (pair axis = wire7)
        crx_j1_j0(xr, xi, C[12], C[13]);                            // C67
        rot_comp(xr, xi, M + 8 * 8, cx[8], sx[8]);                  // G8
        crx_j0_c(xr, xi, C[14], C[15]);                             // C78
        state_swap(xr, xi, 32);
        crx_pair_c(xr, xi, C[16], C[17]);                           // C80 — stay split
    }
    state_swap(xr, xi, 32);  // restore to normal space

    // ---- probabilities and <Z_w> ----
    v2f P[4];
#pragma unroll
    for (int j = 0; j < 4; ++j) P[j] = xr[j]*xr[j] + xi[j]*xi[j];
    float ps[4];
#pragma unroll
    for (int j = 0; j < 4; ++j) ps[j] = P[j].x + P[j].y;
    float psum = ps[0] + ps[1] + ps[2] + ps[3];

    float t = psum;
    float d[6];
#pragma unroll
    for (int bb = 0; bb < 6; ++bb) {
        if (bb < 4) {
#pragma unroll
            for (int jj = 0; jj < 6; ++jj)
                if (jj < bb) d[jj] += xmove(d[jj], 1 << bb);
            float o = xmove(t, 1 << bb);
            d[bb] = ((lane >> bb) & 1) ? (o - t) : (t - o);
            t += o;
        } else {
#pragma unroll
            for (int jj = 0; jj < 6; ++jj)
                if (jj < bb) { float h, l; swpm(d[jj], 1 << bb, h, l); d[jj] = h + l; }
            float h, l; swpm(t, 1 << bb, h, l);
            d[bb] = l - h;
            t = h + l;
        }
    }
    float e6 = (ps[0] + ps[1]) - (ps[2] + ps[3]);
    float e7 = (ps[0] + ps[2]) - (ps[1] + ps[3]);
    float e8 = (P[0].x - P[0].y) + (P[1].x - P[1].y)
             + (P[2].x - P[2].y) + (P[3].x - P[3].y);
#pragma unroll
    for (int m = 1; m < 16; m <<= 1) {
        e6 += xmove(e6, m); e7 += xmove(e7, m); e8 += xmove(e8, m);
    }
    {
        float h, l;
        swpm(e6, 16, h, l); e6 = h + l;  swpm(e6, 32, h, l); e6 = h + l;
        swpm(e7, 16, h, l); e7 = h + l;  swpm(e7, 32, h, l); e7 = h + l;
        swpm(e8, 16, h, l); e8 = h + l;  swpm(e8, 32, h, l); e8 = h + l;
    }

    float ev[NQ];
#pragma unroll
    for (int w = 0; w < 6; ++w) ev[w] = d[5 - w];
    ev[6] = e6; ev[7] = e7; ev[8] = e8;

    // ---- linear head + log_softmax ----
    float lval = -INFINITY;
    if (lane < NC) {
        float dd = fcbs[lane];
        const float* fw = fcw + lane * NQ;
#pragma unroll
        for (int w = 0; w < NQ; ++w) dd += ev[w] * fw[w];
        lval = dd;
    }
    float mx = lval;
    mx = fmaxf(mx, xmove(mx, 1));
    mx = fmaxf(mx, xmove(mx, 2));
    mx = fmaxf(mx, xmove(mx, 4));
    mx = fmaxf(mx, xmove(mx, 8));
    float e = (lane < NC) ? expf(lval - mx) : 0.f;
    float se = e;
    se += xmove(se, 1); se += xmove(se, 2); se += xmove(se, 4); se += xmove(se, 8);
    if (lane < NC) out[b * NC + lane] = lval - mx - logf(se);
}

extern "C" void kernel_launch(void* const* d_in, const int* in_sizes, int n_in,
                              void* d_out, int out_size, void* d_ws, size_t ws_size,
                              hipStream_t stream) {
    const float* x     = (const float*)d_in[0];
    const float* rot_w = (const float*)d_in[1];
    const float* crx_w = (const float*)d_in[2];
    const float* fc_w  = (const float*)d_in[3];
    const float* fc_b  = (const float*)d_in[4];
    float* out = (float*)d_out;
    const int B = in_sizes[0] / NQ;
    const int blocks = (B + 3) / 4;
    qmlp_kernel<<<blocks, 256, 0, stream>>>(x, rot_w, crx_w, fc_w, fc_b, out, B);
}

// Round 10
// 30.876 us; speedup vs baseline: 1.4382x; 1.0060x over previous
//
#include <hip/hip_runtime.h>
#include <math.h>

#define NQ 9
#define NL 5
#define NC 10

typedef float v2f __attribute__((ext_vector_type(2)));
typedef float v4f __attribute__((ext_vector_type(4)));

__device__ __forceinline__ v2f sp(float x) { v2f r; r.x = x; r.y = x; return r; }

// ---- gfx950 permlane pair swap: (a,b) -> (S0 = bitM=0 side, S1 = bitM=1 side) ----
__device__ __forceinline__ void plswap(float& a, float& b, int mask) {
    if (mask == 32) {
        auto r = __builtin_amdgcn_permlane32_swap(__float_as_int(a), __float_as_int(b), false, false);
        a = __int_as_float(r[0]); b = __int_as_float(r[1]);
    } else {
        auto r = __builtin_amdgcn_permlane16_swap(__float_as_int(a), __float_as_int(b), false, false);
        a = __int_as_float(r[0]); b = __int_as_float(r[1]);
    }
}
__device__ __forceinline__ void plswap2(v2f& a, v2f& b, int mask) {
    float ax = a.x, bx = b.x, ay = a.y, by = b.y;
    plswap(ax, bx, mask); plswap(ay, by, mask);
    a.x = ax; a.y = ay; b.x = bx; b.y = by;
}
__device__ __forceinline__ void state_swap(v2f (&xr)[4], v2f (&xi)[4], int mask) {
    plswap2(xr[0], xr[1], mask); plswap2(xr[2], xr[3], mask);
    plswap2(xi[0], xi[1], mask); plswap2(xi[2], xi[3], mask);
}

// ---- broadcast swpm (epilogue only): r[0]=lo-broadcast, r[1]=hi-broadcast ----
__device__ __forceinline__ void swpm(float x, int mask, float& hi, float& lo) {
    if (mask == 32) {
        auto r = __builtin_amdgcn_permlane32_swap(__float_as_int(x), __float_as_int(x), false, false);
        lo = __int_as_float(r[0]); hi = __int_as_float(r[1]);
    } else {
        auto r = __builtin_amdgcn_permlane16_swap(__float_as_int(x), __float_as_int(x), false, false);
        lo = __int_as_float(r[0]); hi = __int_as_float(r[1]);
    }
}

// XOR-lane exchange masks 1,2,4,8 — DPP (VALU, 1-2 ops).
__device__ __forceinline__ float xmove(float x, int mask) {
    if (mask == 1)
        return __int_as_float(__builtin_amdgcn_update_dpp(0, __float_as_int(x), 0xB1, 0xF, 0xF, true));
    if (mask == 2)
        return __int_as_float(__builtin_amdgcn_update_dpp(0, __float_as_int(x), 0x4E, 0xF, 0xF, true));
    if (mask == 4) {
        int t = __builtin_amdgcn_update_dpp(0, __float_as_int(x), 0x104, 0xF, 0x5, false);
        t = __builtin_amdgcn_update_dpp(t, __float_as_int(x), 0x114, 0xF, 0xA, false);
        return __int_as_float(t);
    }
    return __int_as_float(__builtin_amdgcn_update_dpp(0, __float_as_int(x), 0x128, 0xF, 0xF, true));
}
__device__ __forceinline__ v2f xmv2(v2f v, int mask) {
    v2f r; r.x = xmove(v.x, mask); r.y = xmove(v.y, mask); return r;
}

// State packing: lane owns 8 amps as 4 x float2; amp = (j<<1)|comp.
// wire w -> bit 8-w: wires 0..5 -> lane bits 5..0; wire6 -> j bit1; wire7 -> j bit0; wire8 -> comp.
// SU(2): tables store (m00r,m00i,m01r,m01i); m11=conj(m00), m10=-conj(m01).
#define HALF_U(A, c, s)                                               \
    float u00r = A.x*c + s*A.w,  u00i = A.y*c - s*A.z;                \
    float u01r = A.z*c + s*A.y,  u01i = A.w*c - s*A.x;

// ---- uncontrolled fused gate on pair axis (0,1),(2,3) ----
__device__ __forceinline__ void rot_pair(v2f (&xr)[4], v2f (&xi)[4],
                                         const float* __restrict__ m, float c, float s) {
    const v4f A = *(const v4f*)m;
    HALF_U(A, c, s)
#pragma unroll
    for (int p = 0; p < 4; p += 2) {
        const int q = p + 1;
        v2f a0r = xr[p], a0i = xi[p], a1r = xr[q], a1i = xi[q];
        xr[p] = sp(u00r)*a0r - sp(u00i)*a0i + sp(u01r)*a1r - sp(u01i)*a1i;
        xi[p] = sp(u00r)*a0i + sp(u00i)*a0r + sp(u01r)*a1i + sp(u01i)*a1r;
        xr[q] = sp(-u01r)*a0r - sp(u01i)*a0i + sp(u00r)*a1r + sp(u00i)*a1i;
        xi[q] = sp(-u01r)*a0i + sp(u01i)*a0r + sp(u00r)*a1i - sp(u00i)*a1r;
    }
}

// ---- FUSED (CRX·Rot·RX) cross gate: ctrl lane bit CB selects M0/M1; tgt lane bit LB ----
template<int CB, int LB>
__device__ __forceinline__ void fusedC_cross(v2f (&xr)[4], v2f (&xi)[4],
                                             const float* __restrict__ m,
                                             float c, float s, int lane) {
    const v4f A0 = *(const v4f*)m;
    const v4f A1 = *(const v4f*)(m + 4);
    const bool ctrl = (lane >> CB) & 1;
    v4f A;
    A.x = ctrl ? A1.x : A0.x;  A.y = ctrl ? A1.y : A0.y;
    A.z = ctrl ? A1.z : A0.z;  A.w = ctrl ? A1.w : A0.w;
    HALF_U(A, c, s)
    const int bit = (lane >> LB) & 1;
    const float Csr = u00r,  Cpi = u01i;
    const float Csi = bit ? -u00i : u00i;
    const float Cpr = bit ? -u01r : u01r;
#pragma unroll
    for (int j = 0; j < 4; ++j) {
        v2f pr = xmv2(xr[j], 1 << LB);
        v2f pi = xmv2(xi[j], 1 << LB);
        v2f ar = xr[j], ai = xi[j];
        xr[j] = sp(Csr)*ar - sp(Csi)*ai + sp(Cpr)*pr - sp(Cpi)*pi;
        xi[j] = sp(Csr)*ai + sp(Csi)*ar + sp(Cpr)*pi + sp(Cpi)*pr;
    }
}

// ---- FUSED gate on j bit1 (wire6), ctrl = lane bit0 (wire5) ----
__device__ __forceinline__ void fusedC_j1(v2f (&xr)[4], v2f (&xi)[4],
                                          const float* __restrict__ m,
                                          float c, float s, int lane) {
    const v4f A0 = *(const v4f*)m;
    const v4f A1 = *(const v4f*)(m + 4);
    const bool ctrl = lane & 1;
    v4f A;
    A.x = ctrl ? A1.x : A0.x;  A.y = ctrl ? A1.y : A0.y;
    A.z = ctrl ? A1.z : A0.z;  A.w = ctrl ? A1.w : A0.w;
    HALF_U(A, c, s)
#pragma unroll
    for (int j = 0; j < 2; ++j) {
        const int q = j | 2;
        v2f a0r = xr[j], a0i = xi[j], a1r = xr[q], a1i = xi[q];
        xr[j] = sp(u00r)*a0r - sp(u00i)*a0i + sp(u01r)*a1r - sp(u01i)*a1i;
        xi[j] = sp(u00r)*a0i + sp(u00i)*a0r + sp(u01r)*a1i + sp(u01i)*a1r;
        xr[q] = sp(-u01r)*a0r - sp(u01i)*a0i + sp(u00r)*a1r + sp(u00i)*a1i;
        xi[q] = sp(-u01r)*a0i + sp(u01i)*a0r + sp(u00r)*a1i - sp(u00i)*a1r;
    }
}

// ---- uncontrolled fused gate on component bit (wire 8) ----
__device__ __forceinline__ void rot_comp(v2f (&xr)[4], v2f (&xi)[4],
                                         const float* __restrict__ m, float c, float s) {
    const v4f A = *(const v4f*)m;
    HALF_U(A, c, s)
    v2f U0r = { u00r, -u01r }, U0i = { u00i,  u01i };
    v2f U1r = { u01r,  u00r }, U1i = { u01i, -u00i };
#pragma unroll
    for (int j = 0; j < 4; ++j) {
        v2f A0r = xr[j].xx, A0i = xi[j].xx, A1r = xr[j].yy, A1i = xi[j].yy;
        xr[j] = U0r*A0r - U0i*A0i + U1r*A1r - U1i*A1i;
        xi[j] = U0r*A0i + U0i*A0r + U1r*A1i + U1i*A1r;
    }
}

// ---- CRX helpers ----
template<int CB, int M>
__device__ __forceinline__ void crx_dpp(v2f (&xr)[4], v2f (&xi)[4], float c, float s, int lane) {
    const bool ctrl = (lane >> CB) & 1;
    const float ce = ctrl ? c : 1.f;
    const float se = ctrl ? s : 0.f;
#pragma unroll
    for (int j = 0; j < 4; ++j) {
        v2f pr = xmv2(xr[j], M);
        v2f pi = xmv2(xi[j], M);
        xr[j] = sp(ce)*xr[j] + sp(se)*pi;
        xi[j] = sp(ce)*xi[j] - sp(se)*pr;
    }
}
__device__ __forceinline__ void crx_pair_s(v2f (&xr)[4], v2f (&xi)[4], float ce, float se) {
#pragma unroll
    for (int p = 0; p < 4; p += 2) {
        const int q = p + 1;
        v2f a0r = xr[p], a0i = xi[p], a1r = xr[q], a1i = xi[q];
        xr[p] = sp(ce)*a0r + sp(se)*a1i;
        xi[p] = sp(ce)*a0i - sp(se)*a1r;
        xr[q] = sp(ce)*a1r + sp(se)*a0i;
        xi[q] = sp(ce)*a1i - sp(se)*a0r;
    }
}
__device__ __forceinline__ void crx_pair_c(v2f (&xr)[4], v2f (&xi)[4], float c, float s) {
    const v2f cev = {1.f, c};
    const v2f sev = {0.f, s};
#pragma unroll
    for (int p = 0; p < 4; p += 2) {
        const int q = p + 1;
        v2f a0r = xr[p], a0i = xi[p], a1r = xr[q], a1i = xi[q];
        xr[p] = cev*a0r + sev*a1i;
        xi[p] = cev*a0i - sev*a1r;
        xr[q] = cev*a1r + sev*a0i;
        xi[q] = cev*a1i - sev*a0r;
    }
}
__device__ __forceinline__ void crx_l_j1(v2f (&xr)[4], v2f (&xi)[4], float c, float s, int lane) {
    const bool ctrl = lane & 1;
    const float ce = ctrl ? c : 1.f;
    const float se = ctrl ? s : 0.f;
#pragma unroll
    for (int j = 0; j < 2; ++j) {
        const int q = j | 2;
        v2f a0r = xr[j], a0i = xi[j], a1r = xr[q], a1i = xi[q];
        xr[j] = sp(ce)*a0r + sp(se)*a1i;
        xi[j] = sp(ce)*a0i - sp(se)*a1r;
        xr[q] = sp(ce)*a1r + sp(se)*a0i;
        xi[q] = sp(ce)*a1i - sp(se)*a0r;
    }
}
__device__ __forceinline__ void crx_j1_j0(v2f (&xr)[4], v2f (&xi)[4], float c, float s) {
    v2f a0r = xr[2], a0i = xi[2], a1r = xr[3], a1i = xi[3];
    xr[2] = sp(c)*a0r + sp(s)*a1i;
    xi[2] = sp(c)*a0i - sp(s)*a1r;
    xr[3] = sp(c)*a1r + sp(s)*a0i;
    xi[3] = sp(c)*a1i - sp(s)*a0r;
}
__device__ __forceinline__ void crx_j0_c(v2f (&xr)[4], v2f (&xi)[4], float c, float s) {
#pragma unroll
    for (int j = 1; j < 4; j += 2) {
        v2f vr = xr[j], vi = xi[j];
        xr[j] = sp(c)*vr + sp(s)*vi.yx;
        xi[j] = sp(c)*vi - sp(s)*vr.yx;
    }
}

// ---- layer-0 product state for one sample ----
__device__ __forceinline__ void init_state(v2f (&xr)[4], v2f (&xi)[4],
                                           const float* __restrict__ M,
                                           const float (&cx)[NQ], const float (&sx)[NQ],
                                           int lane) {
    float ar = 1.f, ai = 0.f;
#pragma unroll
    for (int w = 0; w < 6; ++w) {
        const v4f A = *(const v4f*)(M + w * 8);
        float c = cx[w], s = sx[w];
        HALF_U(A, c, s)
        int bit = (lane >> (5 - w)) & 1;
        float vr = bit ? -u01r : u00r;
        float vi = bit ?  u01i : u00i;
        float nr = ar * vr - ai * vi;
        float ni = ar * vi + ai * vr;
        ar = nr; ai = ni;
    }
    float vr67[2][2], vi67[2][2];
#pragma unroll
    for (int q = 0; q < 2; ++q) {
        const v4f A = *(const v4f*)(M + (6 + q) * 8);
        float c = cx[6 + q], s = sx[6 + q];
        HALF_U(A, c, s)
        vr67[q][0] = u00r;  vi67[q][0] = u00i;
        vr67[q][1] = -u01r; vi67[q][1] = u01i;
    }
    float t6r[2], t6i[2];
#pragma unroll
    for (int bb = 0; bb < 2; ++bb) {
        t6r[bb] = ar * vr67[0][bb] - ai * vi67[0][bb];
        t6i[bb] = ar * vi67[0][bb] + ai * vr67[0][bb];
    }
    float t67r[4], t67i[4];
#pragma unroll
    for (int j = 0; j < 4; ++j) {
        int b6 = j >> 1, b7 = j & 1;
        t67r[j] = t6r[b6] * vr67[1][b7] - t6i[b6] * vi67[1][b7];
        t67i[j] = t6r[b6] * vi67[1][b7] + t6i[b6] * vr67[1][b7];
    }
    const v4f A = *(const v4f*)(M + 8 * 8);
    float c = cx[8], s = sx[8];
    HALF_U(A, c, s)
    v2f V8r = { u00r, -u01r };
    v2f V8i = { u00i,  u01i };
#pragma unroll
    for (int j = 0; j < 4; ++j) {
        xr[j] = sp(t67r[j])*V8r - sp(t67i[j])*V8i;
        xi[j] = sp(t67r[j])*V8i + sp(t67i[j])*V8r;
    }
}

__global__ __launch_bounds__(256) void qmlp_kernel(
    const float* __restrict__ x, const float* __restrict__ rot_w,
    const float* __restrict__ crx_w, const float* __restrict__ fc_w,
    const float* __restrict__ fc_b, float* __restrict__ out, int B)
{
    // per (n,w): [0..3] = M0 (m00,m01), [4..7] = M1 = RX(theta_{w-1}) * M0
    __shared__ __align__(16) float rotm[NL * NQ * 8];
    __shared__ __align__(16) float crxm[NL * NQ * 2];
    __shared__ float fcw[NC * NQ];
    __shared__ float fcbs[NC];

    const int tid = threadIdx.x;
    if (tid < NL * NQ) {
        const int n = tid / NQ, w = tid % NQ;
        const float phi = rot_w[tid * 3 + 0];
        const float th  = rot_w[tid * 3 + 1];
        const float om  = rot_w[tid * 3 + 2];
        float st, ct; sincosf(0.5f * th, &st, &ct);
        float spo, cpo; sincosf(0.5f * (phi + om), &spo, &cpo);
        float smo, cmo; sincosf(0.5f * (phi - om), &smo, &cmo);
        const float m00r =  ct * cpo, m00i = -ct * spo;
        const float m01r = -st * cmo, m01i = -st * smo;
        float* m = rotm + tid * 8;
        m[0] = m00r; m[1] = m00i; m[2] = m01r; m[3] = m01i;
        const int nb = n * NQ + (w + NQ - 1) % NQ;
        float sq, cq; sincosf(0.5f * crx_w[nb], &sq, &cq);
        m[4] = cq*m00r + sq*m01i;
        m[5] = cq*m00i + sq*m01r;
        m[6] = cq*m01r - sq*m00i;
        m[7] = cq*m01i - sq*m00r;
        float sc, cc; sincosf(0.5f * crx_w[tid], &sc, &cc);
        crxm[tid * 2 + 0] = cc; crxm[tid * 2 + 1] = sc;
    }
    if (tid < NC * NQ) fcw[tid] = fc_w[tid];
    if (tid < NC) fcbs[tid] = fc_b[tid];
    __syncthreads();

    const int lane = tid & 63;
    const int b0 = (blockIdx.x * 4 + (tid >> 6)) * 2;   // 2 samples per wave
    const int b1 = b0 + 1;
    if (b0 >= B) return;

    float cxA[NQ], sxA[NQ], cxB[NQ], sxB[NQ];
#pragma unroll
    for (int w = 0; w < NQ; ++w) __sincosf(0.5f * x[b0 * NQ + w], &sxA[w], &cxA[w]);
#pragma unroll
    for (int w = 0; w < NQ; ++w) __sincosf(0.5f * x[b1 * NQ + w], &sxB[w], &cxB[w]);

    v2f xrA[4], xiA[4], xrB[4], xiB[4];
    init_state(xrA, xiA, rotm, cxA, sxA, lane);
    init_state(xrB, xiB, rotm, cxB, sxB, lane);

    // ---- Layer 0 CRX ring (C01..C80) ----
    {
        const float* C = crxm;
        state_swap(xrA, xiA, 16);
        state_swap(xrB, xiB, 16);
        {
            const bool ctrl = (lane >> 5) & 1;
            const float ce = ctrl ? C[0] : 1.f, se = ctrl ? C[1] : 0.f;
            crx_pair_s(xrA, xiA, ce, se);
            crx_pair_s(xrB, xiB, ce, se);
        }
        state_swap(xrA, xiA, 16);
        state_swap(xrB, xiB, 16);
        crx_dpp<4, 8>(xrA, xiA, C[2],  C[3],  lane);  crx_dpp<4, 8>(xrB, xiB, C[2],  C[3],  lane);
        crx_dpp<3, 4>(xrA, xiA, C[4],  C[5],  lane);  crx_dpp<3, 4>(xrB, xiB, C[4],  C[5],  lane);
        crx_dpp<2, 2>(xrA, xiA, C[6],  C[7],  lane);  crx_dpp<2, 2>(xrB, xiB, C[6],  C[7],  lane);
        crx_dpp<1, 1>(xrA, xiA, C[8],  C[9],  lane);  crx_dpp<1, 1>(xrB, xiB, C[8],  C[9],  lane);
        crx_l_j1     (xrA, xiA, C[10], C[11], lane);  crx_l_j1     (xrB, xiB, C[10], C[11], lane);
        crx_j1_j0    (xrA, xiA, C[12], C[13]);        crx_j1_j0    (xrB, xiB, C[12], C[13]);
        crx_j0_c     (xrA, xiA, C[14], C[15]);        crx_j0_c     (xrB, xiB, C[14], C[15]);
        state_swap(xrA, xiA, 32);
        state_swap(xrB, xiB, 32);
        crx_pair_c(xrA, xiA, C[16], C[17]);
        crx_pair_c(xrB, xiB, C[16], C[17]);
    }

    // ---- Layers 1..4 (enter each layer in split-32 space) ----
    for (int n = 1; n < NL; ++n) {
        const float* M = rotm + n * NQ * 8;
        const float* C = crxm + n * NQ * 2;
        rot_pair(xrA, xiA, M + 0 * 8, cxA[0], sxA[0]);
        rot_pair(xrB, xiB, M + 0 * 8, cxB[0], sxB[0]);
        state_swap(xrA, xiA, 32);
        state_swap(xrB, xiB, 32);
        state_swap(xrA, xiA, 16);
        state_swap(xrB, xiB, 16);
        rot_pair(xrA, xiA, M + 1 * 8, cxA[1], sxA[1]);
        rot_pair(xrB, xiB, M + 1 * 8, cxB[1], sxB[1]);
        {
            const bool ctrl = (lane >> 5) & 1;
            const float ce = ctrl ? C[0] : 1.f, se = ctrl ? C[1] : 0.f;
            crx_pair_s(xrA, xiA, ce, se);
            crx_pair_s(xrB, xiB, ce, se);
        }
        state_swap(xrA, xiA, 16);
        state_swap(xrB, xiB, 16);
        fusedC_cross<4, 3>(xrA, xiA, M + 2 * 8, cxA[2], sxA[2], lane);
        fusedC_cross<4, 3>(xrB, xiB, M + 2 * 8, cxB[2], sxB[2], lane);
        fusedC_cross<3, 2>(xrA, xiA, M + 3 * 8, cxA[3], sxA[3], lane);
        fusedC_cross<3, 2>(xrB, xiB, M + 3 * 8, cxB[3], sxB[3], lane);
        fusedC_cross<2, 1>(xrA, xiA, M + 4 * 8, cxA[4], sxA[4], lane);
        fusedC_cross<2, 1>(xrB, xiB, M + 4 * 8, cxB[4], sxB[4], lane);
        fusedC_cross<1, 0>(xrA, xiA, M + 5 * 8, cxA[5], sxA[5], lane);
        fusedC_cross<1, 0>(xrB, xiB, M + 5 * 8, cxB[5], sxB[5], lane);
        fusedC_j1(xrA, xiA, M + 6 * 8, cxA[6], sxA[6], lane);
        fusedC_j1(xrB, xiB, M + 6 * 8, cxB[6], sxB[6], lane);
        rot_pair(xrA, xiA, M + 7 * 8, cxA[7], sxA[7]);
        rot_pair(xrB, xiB, M + 7 * 8, cxB[7], sxB[7]);
        crx_j1_j0(xrA, xiA, C[12], C[13]);
        crx_j1_j0(xrB, xiB, C[12], C[13]);
        rot_comp(xrA, xiA, M + 8 * 8, cxA[8], sxA[8]);
        rot_comp(xrB, xiB, M + 8 * 8, cxB[8], sxB[8]);
        crx_j0_c(xrA, xiA, C[14], C[15]);
        crx_j0_c(xrB, xiB, C[14], C[15]);
        state_swap(xrA, xiA, 32);
        state_swap(xrB, xiB, 32);
        crx_pair_c(xrA, xiA, C[16], C[17]);
        crx_pair_c(xrB, xiB, C[16], C[17]);
    }
    state_swap(xrA, xiA, 32);
    state_swap(xrB, xiB, 32);

    // ---- probabilities and <Z_w> (both samples interleaved) ----
    v2f PA[4], PB[4];
#pragma unroll
    for (int j = 0; j < 4; ++j) { PA[j] = xrA[j]*xrA[j] + xiA[j]*xiA[j];
                                  PB[j] = xrB[j]*xrB[j] + xiB[j]*xiB[j]; }
    float psA[4], psB[4];
#pragma unroll
    for (int j = 0; j < 4; ++j) { psA[j] = PA[j].x + PA[j].y; psB[j] = PB[j].x + PB[j].y; }
    float tA = psA[0] + psA[1] + psA[2] + psA[3];
    float tB = psB[0] + psB[1] + psB[2] + psB[3];

    float dA[6], dB[6];
#pragma unroll
    for (int bb = 0; bb < 6; ++bb) {
        if (bb < 4) {
#pragma unroll
            for (int jj = 0; jj < 6; ++jj)
                if (jj < bb) { dA[jj] += xmove(dA[jj], 1 << bb); dB[jj] += xmove(dB[jj], 1 << bb); }
            float oA = xmove(tA, 1 << bb);
            float oB = xmove(tB, 1 << bb);
            bool hibit = (lane >> bb) & 1;
            dA[bb] = hibit ? (oA - tA) : (tA - oA);
            dB[bb] = hibit ? (oB - tB) : (tB - oB);
            tA += oA; tB += oB;
        } else {
#pragma unroll
            for (int jj = 0; jj < 6; ++jj)
                if (jj < bb) {
                    float h, l;
                    swpm(dA[jj], 1 << bb, h, l); dA[jj] = h + l;
                    swpm(dB[jj], 1 << bb, h, l); dB[jj] = h + l;
                }
            float hA, lA, hB, lB;
            swpm(tA, 1 << bb, hA, lA);
            swpm(tB, 1 << bb, hB, lB);
            dA[bb] = lA - hA; tA = hA + lA;
            dB[bb] = lB - hB; tB = hB + lB;
        }
    }
    float e6A = (psA[0] + psA[1]) - (psA[2] + psA[3]);
    float e7A = (psA[0] + psA[2]) - (psA[1] + psA[3]);
    float e8A = (PA[0].x - PA[0].y) + (PA[1].x - PA[1].y) + (PA[2].x - PA[2].y) + (PA[3].x - PA[3].y);
    float e6B = (psB[0] + psB[1]) - (psB[2] + psB[3]);
    float e7B = (psB[0] + psB[2]) - (psB[1] + psB[3]);
    float e8B = (PB[0].x - PB[0].y) + (PB[1].x - PB[1].y) + (PB[2].x - PB[2].y) + (PB[3].x - PB[3].y);
#pragma unroll
    for (int m = 1; m < 16; m <<= 1) {
        e6A += xmove(e6A, m); e7A += xmove(e7A, m); e8A += xmove(e8A, m);
        e6B += xmove(e6B, m); e7B += xmove(e7B, m); e8B += xmove(e8B, m);
    }
    {
        float h, l;
        swpm(e6A, 16, h, l); e6A = h + l;  swpm(e6A, 32, h, l); e6A = h + l;
        swpm(e7A, 16, h, l); e7A = h + l;  swpm(e7A, 32, h, l); e7A = h + l;
        swpm(e8A, 16, h, l); e8A = h + l;  swpm(e8A, 32, h, l); e8A = h + l;
        swpm(e6B, 16, h, l); e6B = h + l;  swpm(e6B, 32, h, l); e6B = h + l;
        swpm(e7B, 16, h, l); e7B = h + l;  swpm(e7B, 32, h, l); e7B = h + l;
        swpm(e8B, 16, h, l); e8B = h + l;  swpm(e8B, 32, h, l); e8B = h + l;
    }

    float evA[NQ], evB[NQ];
#pragma unroll
    for (int w = 0; w < 6; ++w) { evA[w] = dA[5 - w]; evB[w] = dB[5 - w]; }
    evA[6] = e6A; evA[7] = e7A; evA[8] = e8A;
    evB[6] = e6B; evB[7] = e7B; evB[8] = e8B;

    // ---- linear head + log_softmax (lane c < 10 owns class c) ----
    float lvA = -INFINITY, lvB = -INFINITY;
    if (lane < NC) {
        float a = fcbs[lane], c2 = a;
        const float* fw = fcw + lane * NQ;
#pragma unroll
        for (int w = 0; w < NQ; ++w) { a += evA[w] * fw[w]; c2 += evB[w] * fw[w]; }
        lvA = a; lvB = c2;
    }
    float mxA = lvA, mxB = lvB;
    mxA = fmaxf(mxA, xmove(mxA, 1)); mxB = fmaxf(mxB, xmove(mxB, 1));
    mxA = fmaxf(mxA, xmove(mxA, 2)); mxB = fmaxf(mxB, xmove(mxB, 2));
    mxA = fmaxf(mxA, xmove(mxA, 4)); mxB = fmaxf(mxB, xmove(mxB, 4));
    mxA = fmaxf(mxA, xmove(mxA, 8)); mxB = fmaxf(mxB, xmove(mxB, 8));
    float eA = (lane < NC) ? expf(lvA - mxA) : 0.f;
    float eB = (lane < NC) ? expf(lvB - mxB) : 0.f;
    float seA = eA, seB = eB;
    seA += xmove(seA, 1); seB += xmove(seB, 1);
    seA += xmove(seA, 2); seB += xmove(seB, 2);
    seA += xmove(seA, 4); seB += xmove(seB, 4);
    seA += xmove(seA, 8); seB += xmove(seB, 8);
    if (lane < NC) {
        out[b0 * NC + lane] = lvA - mxA - logf(seA);
        if (b1 < B) out[b1 * NC + lane] = lvB - mxB - logf(seB);
    }
}

extern "C" void kernel_launch(void* const* d_in, const int* in_sizes, int n_in,
                              void* d_out, int out_size, void* d_ws, size_t ws_size,
                              hipStream_t stream) {
    const float* x     = (const float*)d_in[0];
    const float* rot_w = (const float*)d_in[1];
    const float* crx_w = (const float*)d_in[2];
    const float* fc_w  = (const float*)d_in[3];
    const float* fc_b  = (const float*)d_in[4];
    float* out = (float*)d_out;
    const int B = in_sizes[0] / NQ;
    const int nw = (B + 1) / 2;              // waves (2 samples each)
    const int blocks = (nw + 3) / 4;         // 4 waves per 256-thread block
    qmlp_kernel<<<blocks, 256, 0, stream>>>(x, rot_w, crx_w, fc_w, fc_b, out, B);
}

// Round 11
// 30.170 us; speedup vs baseline: 1.4719x; 1.0234x over previous
//
#include <hip/hip_runtime.h>
#include <math.h>

#define NQ 9
#define NL 5
#define NC 10

typedef float v2f __attribute__((ext_vector_type(2)));
typedef float v4f __attribute__((ext_vector_type(4)));

__device__ __forceinline__ v2f sp(float x) { v2f r; r.x = x; r.y = x; return r; }

// ---- gfx950 permlane pair swap: (a,b) -> (S0 = bitM=0 side, S1 = bitM=1 side) ----
__device__ __forceinline__ void plswap(float& a, float& b, int mask) {
    if (mask == 32) {
        auto r = __builtin_amdgcn_permlane32_swap(__float_as_int(a), __float_as_int(b), false, false);
        a = __int_as_float(r[0]); b = __int_as_float(r[1]);
    } else {
        auto r = __builtin_amdgcn_permlane16_swap(__float_as_int(a), __float_as_int(b), false, false);
        a = __int_as_float(r[0]); b = __int_as_float(r[1]);
    }
}
__device__ __forceinline__ void plswap2(v2f& a, v2f& b, int mask) {
    float ax = a.x, bx = b.x, ay = a.y, by = b.y;
    plswap(ax, bx, mask); plswap(ay, by, mask);
    a.x = ax; a.y = ay; b.x = bx; b.y = by;
}
__device__ __forceinline__ void state_swap(v2f (&xr)[4], v2f (&xi)[4], int mask) {
    plswap2(xr[0], xr[1], mask); plswap2(xr[2], xr[3], mask);
    plswap2(xi[0], xi[1], mask); plswap2(xi[2], xi[3], mask);
}

// ---- broadcast swpm (epilogue only): r[0]=lo-broadcast, r[1]=hi-broadcast ----
__device__ __forceinline__ void swpm(float x, int mask, float& hi, float& lo) {
    if (mask == 32) {
        auto r = __builtin_amdgcn_permlane32_swap(__float_as_int(x), __float_as_int(x), false, false);
        lo = __int_as_float(r[0]); hi = __int_as_float(r[1]);
    } else {
        auto r = __builtin_amdgcn_permlane16_swap(__float_as_int(x), __float_as_int(x), false, false);
        lo = __int_as_float(r[0]); hi = __int_as_float(r[1]);
    }
}

// XOR-lane exchange masks 1,2,4,8 — DPP (VALU, 1-2 ops).
__device__ __forceinline__ float xmove(float x, int mask) {
    if (mask == 1)
        return __int_as_float(__builtin_amdgcn_update_dpp(0, __float_as_int(x), 0xB1, 0xF, 0xF, true));
    if (mask == 2)
        return __int_as_float(__builtin_amdgcn_update_dpp(0, __float_as_int(x), 0x4E, 0xF, 0xF, true));
    if (mask == 4) {
        int t = __builtin_amdgcn_update_dpp(0, __float_as_int(x), 0x104, 0xF, 0x5, false);
        t = __builtin_amdgcn_update_dpp(t, __float_as_int(x), 0x114, 0xF, 0xA, false);
        return __int_as_float(t);
    }
    return __int_as_float(__builtin_amdgcn_update_dpp(0, __float_as_int(x), 0x128, 0xF, 0xF, true));
}
__device__ __forceinline__ v2f xmv2(v2f v, int mask) {
    v2f r; r.x = xmove(v.x, mask); r.y = xmove(v.y, mask); return r;
}

// State packing: lane owns 8 amps as 4 x float2; amp = (j<<1)|comp.
// wire w -> bit 8-w: wires 0..5 -> lane bits 5..0; wire6 -> j bit1; wire7 -> j bit0; wire8 -> comp.
// SU(2): tables store (m00r,m00i,m01r,m01i); m11=conj(m00), m10=-conj(m01).
// Per (n,w): m[0..3] = M0 (Rot), m[4..7] = M1 = RX(theta_{w-1}) * M0.
#define HALF_U(A, c, s)                                               \
    float u00r = A.x*c + s*A.w,  u00i = A.y*c - s*A.z;                \
    float u01r = A.z*c + s*A.y,  u01i = A.w*c - s*A.x;

#define PAIR_BODY(p, q)                                                       \
    {                                                                         \
        v2f a0r = xr[p], a0i = xi[p], a1r = xr[q], a1i = xi[q];               \
        xr[p] = sp(u00r)*a0r - sp(u00i)*a0i + sp(u01r)*a1r - sp(u01i)*a1i;    \
        xi[p] = sp(u00r)*a0i + sp(u00i)*a0r + sp(u01r)*a1i + sp(u01i)*a1r;    \
        xr[q] = sp(-u01r)*a0r - sp(u01i)*a0i + sp(u00r)*a1r + sp(u00i)*a1i;   \
        xi[q] = sp(-u01r)*a0i + sp(u01i)*a0r + sp(u00r)*a1i - sp(u00i)*a1r;   \
    }

// ---- G7·C67 fused: pair axis = wire7; pair(0,1) ctrl=0 -> A0, pair(2,3) ctrl=1 -> A1 ----
__device__ __forceinline__ void rot_pair_dual(v2f (&xr)[4], v2f (&xi)[4],
                                              const float* __restrict__ m, float c, float s) {
    const v4f A0 = *(const v4f*)m;
    const v4f A1 = *(const v4f*)(m + 4);
    { HALF_U(A0, c, s) PAIR_BODY(0, 1) }
    { HALF_U(A1, c, s) PAIR_BODY(2, 3) }
}

// ---- G1·C01 fused: split-16 pair gate, matrix selected by ctrl (wire0 = lane bit5) ----
__device__ __forceinline__ void rot_pair_sel(v2f (&xr)[4], v2f (&xi)[4],
                                             const float* __restrict__ m, float c, float s,
                                             bool ctrl) {
    const v4f A0 = *(const v4f*)m;
    const v4f A1 = *(const v4f*)(m + 4);
    v4f A;
    A.x = ctrl ? A1.x : A0.x;  A.y = ctrl ? A1.y : A0.y;
    A.z = ctrl ? A1.z : A0.z;  A.w = ctrl ? A1.w : A0.w;
    HALF_U(A, c, s)
    PAIR_BODY(0, 1)
    PAIR_BODY(2, 3)
}

// ---- G0·C80(prev) fused: split-32 pair gate with per-component (c,s):
//      comp 0: RX(x0); comp 1: RX(x0 + theta8_prev)  [RX angles add] ----
__device__ __forceinline__ void rot_pair_v2(v2f (&xr)[4], v2f (&xi)[4],
                                            const float* __restrict__ m, v2f c, v2f s) {
    const v4f A = *(const v4f*)m;
    v2f u00r = sp(A.x)*c + s*sp(A.w);
    v2f u00i = sp(A.y)*c - s*sp(A.z);
    v2f u01r = sp(A.z)*c + s*sp(A.y);
    v2f u01i = sp(A.w)*c - s*sp(A.x);
#pragma unroll
    for (int p = 0; p < 4; p += 2) {
        const int q = p + 1;
        v2f a0r = xr[p], a0i = xi[p], a1r = xr[q], a1i = xi[q];
        xr[p] = u00r*a0r - u00i*a0i + u01r*a1r - u01i*a1i;
        xi[p] = u00r*a0i + u00i*a0r + u01r*a1i + u01i*a1r;
        xr[q] = -u01r*a0r - u01i*a0i + u00r*a1r + u00i*a1i;
        xi[q] = -u01r*a0i + u01i*a0r + u00r*a1i - u00i*a1r;
    }
}

// ---- G8·C78 fused: component axis; even j -> A0, odd j -> A1 (compile-time select) ----
__device__ __forceinline__ void rot_comp_dual(v2f (&xr)[4], v2f (&xi)[4],
                                              const float* __restrict__ m, float c, float s) {
    const v4f A0v = *(const v4f*)m;
    const v4f A1v = *(const v4f*)(m + 4);
    v2f U0r0, U0i0, U1r0, U1i0, U0r1, U0i1, U1r1, U1i1;
    { HALF_U(A0v, c, s)
      U0r0 = (v2f){ u00r, -u01r }; U0i0 = (v2f){ u00i,  u01i };
      U1r0 = (v2f){ u01r,  u00r }; U1i0 = (v2f){ u01i, -u00i }; }
    { HALF_U(A1v, c, s)
      U0r1 = (v2f){ u00r, -u01r }; U0i1 = (v2f){ u00i,  u01i };
      U1r1 = (v2f){ u01r,  u00r }; U1i1 = (v2f){ u01i, -u00i }; }
#pragma unroll
    for (int j = 0; j < 4; ++j) {
        v2f U0r = (j & 1) ? U0r1 : U0r0;
        v2f U0i = (j & 1) ? U0i1 : U0i0;
        v2f U1r = (j & 1) ? U1r1 : U1r0;
        v2f U1i = (j & 1) ? U1i1 : U1i0;
        v2f A0r = xr[j].xx, A0i = xi[j].xx, A1r = xr[j].yy, A1i = xi[j].yy;
        xr[j] = U0r*A0r - U0i*A0i + U1r*A1r - U1i*A1i;
        xi[j] = U0r*A0i + U0i*A0r + U1r*A1i + U1i*A1r;
    }
}

// ---- FUSED (CRX·Rot·RX) cross gate: ctrl lane bit CB selects M0/M1; tgt lane bit LB ----
template<int CB, int LB>
__device__ __forceinline__ void fusedC_cross(v2f (&xr)[4], v2f (&xi)[4],
                                             const float* __restrict__ m,
                                             float c, float s, int lane) {
    const v4f A0 = *(const v4f*)m;
    const v4f A1 = *(const v4f*)(m + 4);
    const bool ctrl = (lane >> CB) & 1;
    v4f A;
    A.x = ctrl ? A1.x : A0.x;  A.y = ctrl ? A1.y : A0.y;
    A.z = ctrl ? A1.z : A0.z;  A.w = ctrl ? A1.w : A0.w;
    HALF_U(A, c, s)
    const int bit = (lane >> LB) & 1;
    const float Csr = u00r,  Cpi = u01i;
    const float Csi = bit ? -u00i : u00i;
    const float Cpr = bit ? -u01r : u01r;
#pragma unroll
    for (int j = 0; j < 4; ++j) {
        v2f pr = xmv2(xr[j], 1 << LB);
        v2f pi = xmv2(xi[j], 1 << LB);
        v2f ar = xr[j], ai = xi[j];
        xr[j] = sp(Csr)*ar - sp(Csi)*ai + sp(Cpr)*pr - sp(Cpi)*pi;
        xi[j] = sp(Csr)*ai + sp(Csi)*ar + sp(Cpr)*pi + sp(Cpi)*pr;
    }
}

// ---- G6·C56 fused on j bit1 (wire6), ctrl = lane bit0 (wire5) ----
__device__ __forceinline__ void fusedC_j1(v2f (&xr)[4], v2f (&xi)[4],
                                          const float* __restrict__ m,
                                          float c, float s, int lane) {
    const v4f A0 = *(const v4f*)m;
    const v4f A1 = *(const v4f*)(m + 4);
    const bool ctrl = lane & 1;
    v4f A;
    A.x = ctrl ? A1.x : A0.x;  A.y = ctrl ? A1.y : A0.y;
    A.z = ctrl ? A1.z : A0.z;  A.w = ctrl ? A1.w : A0.w;
    HALF_U(A, c, s)
#pragma unroll
    for (int j = 0; j < 2; ++j) {
        const int q = j | 2;
        v2f a0r = xr[j], a0i = xi[j], a1r = xr[q], a1i = xi[q];
        xr[j] = sp(u00r)*a0r - sp(u00i)*a0i + sp(u01r)*a1r - sp(u01i)*a1i;
        xi[j] = sp(u00r)*a0i + sp(u00i)*a0r + sp(u01r)*a1i + sp(u01i)*a1r;
        xr[q] = sp(-u01r)*a0r - sp(u01i)*a0i + sp(u00r)*a1r + sp(u00i)*a1i;
        xi[q] = sp(-u01r)*a0i + sp(u01i)*a0r + sp(u00r)*a1i - sp(u00i)*a1r;
    }
}

// ---- CRX helpers (layer-0 ring + final C80) ----
template<int CB, int M>
__device__ __forceinline__ void crx_dpp(v2f (&xr)[4], v2f (&xi)[4], float c, float s, int lane) {
    const bool ctrl = (lane >> CB) & 1;
    const float ce = ctrl ? c : 1.f;
    const float se = ctrl ? s : 0.f;
#pragma unroll
    for (int j = 0; j < 4; ++j) {
        v2f pr = xmv2(xr[j], M);
        v2f pi = xmv2(xi[j], M);
        xr[j] = sp(ce)*xr[j] + sp(se)*pi;
        xi[j] = sp(ce)*xi[j] - sp(se)*pr;
    }
}
__device__ __forceinline__ void crx_pair_s(v2f (&xr)[4], v2f (&xi)[4], float ce, float se) {
#pragma unroll
    for (int p = 0; p < 4; p += 2) {
        const int q = p + 1;
        v2f a0r = xr[p], a0i = xi[p], a1r = xr[q], a1i = xi[q];
        xr[p] = sp(ce)*a0r + sp(se)*a1i;
        xi[p] = sp(ce)*a0i - sp(se)*a1r;
        xr[q] = sp(ce)*a1r + sp(se)*a0i;
        xi[q] = sp(ce)*a1i - sp(se)*a0r;
    }
}
__device__ __forceinline__ void crx_pair_c(v2f (&xr)[4], v2f (&xi)[4], float c, float s) {
    const v2f cev = {1.f, c};
    const v2f sev = {0.f, s};
#pragma unroll
    for (int p = 0; p < 4; p += 2) {
        const int q = p + 1;
        v2f a0r = xr[p], a0i = xi[p], a1r = xr[q], a1i = xi[q];
        xr[p] = cev*a0r + sev*a1i;
        xi[p] = cev*a0i - sev*a1r;
        xr[q] = cev*a1r + sev*a0i;
        xi[q] = cev*a1i - sev*a0r;
    }
}
__device__ __forceinline__ void crx_l_j1(v2f (&xr)[4], v2f (&xi)[4], float c, float s, int lane) {
    const bool ctrl = lane & 1;
    const float ce = ctrl ? c : 1.f;
    const float se = ctrl ? s : 0.f;
#pragma unroll
    for (int j = 0; j < 2; ++j) {
        const int q = j | 2;
        v2f a0r = xr[j], a0i = xi[j], a1r = xr[q], a1i = xi[q];
        xr[j] = sp(ce)*a0r + sp(se)*a1i;
        xi[j] = sp(ce)*a0i - sp(se)*a1r;
        xr[q] = sp(ce)*a1r + sp(se)*a0i;
        xi[q] = sp(ce)*a1i - sp(se)*a0r;
    }
}
__device__ __forceinline__ void crx_j1_j0(v2f (&xr)[4], v2f (&xi)[4], float c, float s) {
    v2f a0r = xr[2], a0i = xi[2], a1r = xr[3], a1i = xi[3];
    xr[2] = sp(c)*a0r + sp(s)*a1i;
    xi[2] = sp(c)*a0i - sp(s)*a1r;
    xr[3] = sp(c)*a1r + sp(s)*a0i;
    xi[3] = sp(c)*a1i - sp(s)*a0r;
}
__device__ __forceinline__ void crx_j0_c(v2f (&xr)[4], v2f (&xi)[4], float c, float s) {
#pragma unroll
    for (int j = 1; j < 4; j += 2) {
        v2f vr = xr[j], vi = xi[j];
        xr[j] = sp(c)*vr + sp(s)*vi.yx;
        xi[j] = sp(c)*vi - sp(s)*vr.yx;
    }
}

__global__ __launch_bounds__(256) void qmlp_kernel(
    const float* __restrict__ x, const float* __restrict__ rot_w,
    const float* __restrict__ crx_w, const float* __restrict__ fc_w,
    const float* __restrict__ fc_b, float* __restrict__ out, int B)
{
    __shared__ __align__(16) float rotm[NL * NQ * 8];
    __shared__ __align__(16) float crxm[NL * NQ * 2];
    __shared__ float fcw[NC * NQ];
    __shared__ float fcbs[NC];

    const int tid = threadIdx.x;
    if (tid < NL * NQ) {
        const int n = tid / NQ, w = tid % NQ;
        const float phi = rot_w[tid * 3 + 0];
        const float th  = rot_w[tid * 3 + 1];
        const float om  = rot_w[tid * 3 + 2];
        float st, ct; sincosf(0.5f * th, &st, &ct);
        float spo, cpo; sincosf(0.5f * (phi + om), &spo, &cpo);
        float smo, cmo; sincosf(0.5f * (phi - om), &smo, &cmo);
        const float m00r =  ct * cpo, m00i = -ct * spo;
        const float m01r = -st * cmo, m01i = -st * smo;
        float* m = rotm + tid * 8;
        m[0] = m00r; m[1] = m00i; m[2] = m01r; m[3] = m01i;
        const int nb = n * NQ + (w + NQ - 1) % NQ;
        float sq, cq; sincosf(0.5f * crx_w[nb], &sq, &cq);
        m[4] = cq*m00r + sq*m01i;
        m[5] = cq*m00i + sq*m01r;
        m[6] = cq*m01r - sq*m00i;
        m[7] = cq*m01i - sq*m00r;
        float sc, cc; sincosf(0.5f * crx_w[tid], &sc, &cc);
        crxm[tid * 2 + 0] = cc; crxm[tid * 2 + 1] = sc;
    }
    if (tid < NC * NQ) fcw[tid] = fc_w[tid];
    if (tid < NC) fcbs[tid] = fc_b[tid];
    __syncthreads();

    const int lane = tid & 63;
    const int b = blockIdx.x * 4 + (tid >> 6);
    if (b >= B) return;

    float cx[NQ], sx[NQ];
#pragma unroll
    for (int w = 0; w < NQ; ++w) __sincosf(0.5f * x[b * NQ + w], &sx[w], &cx[w]);

    v2f xr[4], xi[4];

    // ---- Layer 0 single-qubit block on |0..0>: direct product state (SU2 columns) ----
    {
        const float* M = rotm;
        float ar = 1.f, ai = 0.f;
#pragma unroll
        for (int w = 0; w < 6; ++w) {
            const v4f A = *(const v4f*)(M + w * 8);
            float c = cx[w], s = sx[w];
            HALF_U(A, c, s)
            int bit = (lane >> (5 - w)) & 1;
            float vr = bit ? -u01r : u00r;
            float vi = bit ?  u01i : u00i;
            float nr = ar * vr - ai * vi;
            float ni = ar * vi + ai * vr;
            ar = nr; ai = ni;
        }
        float vr67[2][2], vi67[2][2];
#pragma unroll
        for (int q = 0; q < 2; ++q) {
            const v4f A = *(const v4f*)(M + (6 + q) * 8);
            float c = cx[6 + q], s = sx[6 + q];
            HALF_U(A, c, s)
            vr67[q][0] = u00r;  vi67[q][0] = u00i;
            vr67[q][1] = -u01r; vi67[q][1] = u01i;
        }
        float t6r[2], t6i[2];
#pragma unroll
        for (int bb = 0; bb < 2; ++bb) {
            t6r[bb] = ar * vr67[0][bb] - ai * vi67[0][bb];
            t6i[bb] = ar * vi67[0][bb] + ai * vr67[0][bb];
        }
        float t67r[4], t67i[4];
#pragma unroll
        for (int j = 0; j < 4; ++j) {
            int b6 = j >> 1, b7 = j & 1;
            t67r[j] = t6r[b6] * vr67[1][b7] - t6i[b6] * vi67[1][b7];
            t67i[j] = t6r[b6] * vi67[1][b7] + t6i[b6] * vr67[1][b7];
        }
        {
            const v4f A = *(const v4f*)(M + 8 * 8);
            float c = cx[8], s = sx[8];
            HALF_U(A, c, s)
            v2f V8r = { u00r, -u01r };
            v2f V8i = { u00i,  u01i };
#pragma unroll
            for (int j = 0; j < 4; ++j) {
                xr[j] = sp(t67r[j])*V8r - sp(t67i[j])*V8i;
                xi[j] = sp(t67r[j])*V8i + sp(t67i[j])*V8r;
            }
        }
    }

    // ---- Layer 0 CRX ring (C01..C78; C80 deferred into layer 1's G0) ----
    {
        const float* C = crxm;
        state_swap(xr, xi, 16);
        {
            const bool ctrl = (lane >> 5) & 1;
            crx_pair_s(xr, xi, ctrl ? C[0] : 1.f, ctrl ? C[1] : 0.f);   // C01
        }
        state_swap(xr, xi, 16);
        crx_dpp<4, 8>(xr, xi, C[2],  C[3],  lane);  // C12
        crx_dpp<3, 4>(xr, xi, C[4],  C[5],  lane);  // C23
        crx_dpp<2, 2>(xr, xi, C[6],  C[7],  lane);  // C34
        crx_dpp<1, 1>(xr, xi, C[8],  C[9],  lane);  // C45
        crx_l_j1     (xr, xi, C[10], C[11], lane);  // C56
        crx_j1_j0    (xr, xi, C[12], C[13]);        // C67
        crx_j0_c     (xr, xi, C[14], C[15]);        // C78
        state_swap(xr, xi, 32);                      // enter split-32 (C80 fused ahead)
    }

    // ---- Layers 1..4: 9 fused gates each; enter in split-32 space ----
    for (int n = 1; n < NL; ++n) {
        const float* M  = rotm + n * NQ * 8;
        const float* C  = crxm + n * NQ * 2;
        const float* Cp = crxm + (n - 1) * NQ * 2;   // prev layer's C80 angle
        // G0·C80(n-1): comp0 angle x0, comp1 angle x0+theta8(n-1)
        {
            v2f cv, sv;
            cv.x = cx[0];
            sv.x = sx[0];
            cv.y = cx[0]*Cp[16] - sx[0]*Cp[17];
            sv.y = sx[0]*Cp[16] + cx[0]*Cp[17];
            rot_pair_v2(xr, xi, M + 0 * 8, cv, sv);
        }
        state_swap(xr, xi, 32);
        state_swap(xr, xi, 16);
        rot_pair_sel(xr, xi, M + 1 * 8, cx[1], sx[1], (lane >> 5) & 1);  // G1·C01
        state_swap(xr, xi, 16);
        fusedC_cross<4, 3>(xr, xi, M + 2 * 8, cx[2], sx[2], lane);  // G2·C12
        fusedC_cross<3, 2>(xr, xi, M + 3 * 8, cx[3], sx[3], lane);  // G3·C23
        fusedC_cross<2, 1>(xr, xi, M + 4 * 8, cx[4], sx[4], lane);  // G4·C34
        fusedC_cross<1, 0>(xr, xi, M + 5 * 8, cx[5], sx[5], lane);  // G5·C45
        fusedC_j1(xr, xi, M + 6 * 8, cx[6], sx[6], lane);           // G6·C56
        rot_pair_dual(xr, xi, M + 7 * 8, cx[7], sx[7]);             // G7·C67
        rot_comp_dual(xr, xi, M + 8 * 8, cx[8], sx[8]);             // G8·C78
        state_swap(xr, xi, 32);                                     // split-32 for next G0
    }
    // final layer-4 C80 (no following gate), then restore
    crx_pair_c(xr, xi, crxm[4 * NQ * 2 + 16], crxm[4 * NQ * 2 + 17]);
    state_swap(xr, xi, 32);

    // ---- probabilities and <Z_w> ----
    v2f P[4];
#pragma unroll
    for (int j = 0; j < 4; ++j) P[j] = xr[j]*xr[j] + xi[j]*xi[j];
    float ps[4];
#pragma unroll
    for (int j = 0; j < 4; ++j) ps[j] = P[j].x + P[j].y;
    float psum = ps[0] + ps[1] + ps[2] + ps[3];

    float t = psum;
    float d[6];
#pragma unroll
    for (int bb = 0; bb < 6; ++bb) {
        if (bb < 4) {
#pragma unroll
            for (int jj = 0; jj < 6; ++jj)
                if (jj < bb) d[jj] += xmove(d[jj], 1 << bb);
            float o = xmove(t, 1 << bb);
            d[bb] = ((lane >> bb) & 1) ? (o - t) : (t - o);
            t += o;
        } else {
#pragma unroll
            for (int jj = 0; jj < 6; ++jj)
                if (jj < bb) { float h, l; swpm(d[jj], 1 << bb, h, l); d[jj] = h + l; }
            float h, l; swpm(t, 1 << bb, h, l);
            d[bb] = l - h;
            t = h + l;
        }
    }
    float e6 = (ps[0] + ps[1]) - (ps[2] + ps[3]);
    float e7 = (ps[0] + ps[2]) - (ps[1] + ps[3]);
    float e8 = (P[0].x - P[0].y) + (P[1].x - P[1].y)
             + (P[2].x - P[2].y) + (P[3].x - P[3].y);
#pragma unroll
    for (int m = 1; m < 16; m <<= 1) {
        e6 += xmove(e6, m); e7 += xmove(e7, m); e8 += xmove(e8, m);
    }
    {
        float h, l;
        swpm(e6, 16, h, l); e6 = h + l;  swpm(e6, 32, h, l); e6 = h + l;
        swpm(e7, 16, h, l); e7 = h + l;  swpm(e7, 32, h, l); e7 = h + l;
        swpm(e8, 16, h, l); e8 = h + l;  swpm(e8, 32, h, l); e8 = h + l;
    }

    float ev[NQ];
#pragma unroll
    for (int w = 0; w < 6; ++w) ev[w] = d[5 - w];
    ev[6] = e6; ev[7] = e7; ev[8] = e8;

    // ---- linear head + log_softmax ----
    float lval = -INFINITY;
    if (lane < NC) {
        float dd = fcbs[lane];
        const float* fw = fcw + lane * NQ;
#pragma unroll
        for (int w = 0; w < NQ; ++w) dd += ev[w] * fw[w];
        lval = dd;
    }
    float mx = lval;
    mx = fmaxf(mx, xmove(mx, 1));
    mx = fmaxf(mx, xmove(mx, 2));
    mx = fmaxf(mx, xmove(mx, 4));
    mx = fmaxf(mx, xmove(mx, 8));
    float e = (lane < NC) ? expf(lval - mx) : 0.f;
    float se = e;
    se += xmove(se, 1); se += xmove(se, 2); se += xmove(se, 4); se += xmove(se, 8);
    if (lane < NC) out[b * NC + lane] = lval - mx - logf(se);
}

extern "C" void kernel_launch(void* const* d_in, const int* in_sizes, int n_in,
                              void* d_out, int out_size, void* d_ws, size_t ws_size,
                              hipStream_t stream) {
    const float* x     = (const float*)d_in[0];
    const float* rot_w = (const float*)d_in[1];
    const float* crx_w = (const float*)d_in[2];
    const float* fc_w  = (const float*)d_in[3];
    const float* fc_b  = (const float*)d_in[4];
    float* out = (float*)d_out;
    const int B = in_sizes[0] / NQ;
    const int blocks = (B + 3) / 4;
    qmlp_kernel<<<blocks, 256, 0, stream>>>(x, rot_w, crx_w, fc_w, fc_b, out, B);
}

// Round 12
// 27.091 us; speedup vs baseline: 1.6391x; 1.1136x over previous
//
#include <hip/hip_runtime.h>
#include <math.h>

#define NQ 9
#define NL 5
#define NC 10

typedef float v2f __attribute__((ext_vector_type(2)));
typedef float v4f __attribute__((ext_vector_type(4)));

__device__ __forceinline__ v2f sp(float x) { v2f r; r.x = x; r.y = x; return r; }

// ---- gfx950 permlane pair swap: (a,b) -> (S0 = bitM=0 side, S1 = bitM=1 side) ----
__device__ __forceinline__ void plswap(float& a, float& b, int mask) {
    if (mask == 32) {
        auto r = __builtin_amdgcn_permlane32_swap(__float_as_int(a), __float_as_int(b), false, false);
        a = __int_as_float(r[0]); b = __int_as_float(r[1]);
    } else {
        auto r = __builtin_amdgcn_permlane16_swap(__float_as_int(a), __float_as_int(b), false, false);
        a = __int_as_float(r[0]); b = __int_as_float(r[1]);
    }
}
__device__ __forceinline__ void plswap2(v2f& a, v2f& b, int mask) {
    float ax = a.x, bx = b.x, ay = a.y, by = b.y;
    plswap(ax, bx, mask); plswap(ay, by, mask);
    a.x = ax; a.y = ay; b.x = bx; b.y = by;
}
__device__ __forceinline__ void state_swap(v2f (&xr)[4], v2f (&xi)[4], int mask) {
    plswap2(xr[0], xr[1], mask); plswap2(xr[2], xr[3], mask);
    plswap2(xi[0], xi[1], mask); plswap2(xi[2], xi[3], mask);
}

// ---- broadcast swpm (epilogue only): r[0]=lo-broadcast, r[1]=hi-broadcast ----
__device__ __forceinline__ void swpm(float x, int mask, float& hi, float& lo) {
    if (mask == 32) {
        auto r = __builtin_amdgcn_permlane32_swap(__float_as_int(x), __float_as_int(x), false, false);
        lo = __int_as_float(r[0]); hi = __int_as_float(r[1]);
    } else {
        auto r = __builtin_amdgcn_permlane16_swap(__float_as_int(x), __float_as_int(x), false, false);
        lo = __int_as_float(r[0]); hi = __int_as_float(r[1]);
    }
}

// XOR-lane exchange masks 1,2,4,8 — DPP (VALU).
__device__ __forceinline__ float xmove(float x, int mask) {
    if (mask == 1)
        return __int_as_float(__builtin_amdgcn_update_dpp(0, __float_as_int(x), 0xB1, 0xF, 0xF, true));
    if (mask == 2)
        return __int_as_float(__builtin_amdgcn_update_dpp(0, __float_as_int(x), 0x4E, 0xF, 0xF, true));
    if (mask == 4) {
        int t = __builtin_amdgcn_update_dpp(0, __float_as_int(x), 0x104, 0xF, 0x5, false);
        t = __builtin_amdgcn_update_dpp(t, __float_as_int(x), 0x114, 0xF, 0xA, false);
        return __int_as_float(t);
    }
    return __int_as_float(__builtin_amdgcn_update_dpp(0, __float_as_int(x), 0x128, 0xF, 0xF, true));
}
__device__ __forceinline__ v2f xmv2(v2f v, int mask) {
    v2f r; r.x = xmove(v.x, mask); r.y = xmove(v.y, mask); return r;
}

// State packing: lane owns 8 amps as 4 x float2; amp = (j<<1)|comp.
// wire w -> bit 8-w: wires 0..5 -> lane bits 5..0; wire6 -> j bit1; wire7 -> j bit0; wire8 -> comp.
// Precomputed per (sample, n, w): SU(2) matrices as (u00r,u00i,u01r,u01i):
//   slot[0..3] = U0 = M0*RX(x_w), slot[4..7] = U1 = (RX(th_{w-1})*M0)*RX(x_w);
//   w==0,n>=1: interleaved per-comp packing {u00r0,u00r1,u00i0,u00i1,u01r0,u01r1,u01i0,u01i1}
//   with comp1 matrix = U0*RX(th8(n-1)).
#define SET_U(Uv) float u00r=(Uv).x, u00i=(Uv).y, u01r=(Uv).z, u01i=(Uv).w;

#define PAIR_BODY(p, q)                                                       \
    {                                                                         \
        v2f a0r = xr[p], a0i = xi[p], a1r = xr[q], a1i = xi[q];               \
        xr[p] = sp(u00r)*a0r - sp(u00i)*a0i + sp(u01r)*a1r - sp(u01i)*a1i;    \
        xi[p] = sp(u00r)*a0i + sp(u00i)*a0r + sp(u01r)*a1i + sp(u01i)*a1r;    \
        xr[q] = sp(-u01r)*a0r - sp(u01i)*a0i + sp(u00r)*a1r + sp(u00i)*a1i;   \
        xi[q] = sp(-u01r)*a0i + sp(u01i)*a0r + sp(u00r)*a1i - sp(u00i)*a1r;   \
    }

// ---- G7·C67: pair axis = wire7; pair(0,1) -> U0, pair(2,3) -> U1 ----
__device__ __forceinline__ void rot_pair_dualU(v2f (&xr)[4], v2f (&xi)[4],
                                               const float* __restrict__ m) {
    const v4f A0 = *(const v4f*)m;
    const v4f A1 = *(const v4f*)(m + 4);
    { SET_U(A0) PAIR_BODY(0, 1) }
    { SET_U(A1) PAIR_BODY(2, 3) }
}

// ---- G1·C01: split-16 pair gate, matrix selected by ctrl (wire0 = lane bit5) ----
__device__ __forceinline__ void rot_pair_selU(v2f (&xr)[4], v2f (&xi)[4],
                                              const float* __restrict__ m, bool ctrl) {
    const v4f A0 = *(const v4f*)m;
    const v4f A1 = *(const v4f*)(m + 4);
    v4f A;
    A.x = ctrl ? A1.x : A0.x;  A.y = ctrl ? A1.y : A0.y;
    A.z = ctrl ? A1.z : A0.z;  A.w = ctrl ? A1.w : A0.w;
    SET_U(A)
    PAIR_BODY(0, 1)
    PAIR_BODY(2, 3)
}

// ---- G0·C80(prev): split-32 pair gate, per-component matrices (pre-interleaved) ----
__device__ __forceinline__ void rot_pair_v2pk(v2f (&xr)[4], v2f (&xi)[4],
                                              const float* __restrict__ m) {
    const v4f P0 = *(const v4f*)m;        // {u00r0,u00r1,u00i0,u00i1}
    const v4f P1 = *(const v4f*)(m + 4);  // {u01r0,u01r1,u01i0,u01i1}
    v2f u00r = P0.xy, u00i = P0.zw, u01r = P1.xy, u01i = P1.zw;
#pragma unroll
    for (int p = 0; p < 4; p += 2) {
        const int q = p + 1;
        v2f a0r = xr[p], a0i = xi[p], a1r = xr[q], a1i = xi[q];
        xr[p] = u00r*a0r - u00i*a0i + u01r*a1r - u01i*a1i;
        xi[p] = u00r*a0i + u00i*a0r + u01r*a1i + u01i*a1r;
        xr[q] = -u01r*a0r - u01i*a0i + u00r*a1r + u00i*a1i;
        xi[q] = -u01r*a0i + u01i*a0r + u00r*a1i - u00i*a1r;
    }
}

// ---- G8·C78: component axis; even j -> U0, odd j -> U1 ----
__device__ __forceinline__ void rot_comp_dualU(v2f (&xr)[4], v2f (&xi)[4],
                                               const float* __restrict__ m) {
    const v4f A0 = *(const v4f*)m;
    const v4f A1 = *(const v4f*)(m + 4);
    v2f U0r0 = { A0.x, -A0.z }, U0i0 = { A0.y,  A0.w };
    v2f U1r0 = { A0.z,  A0.x }, U1i0 = { A0.w, -A0.y };
    v2f U0r1 = { A1.x, -A1.z }, U0i1 = { A1.y,  A1.w };
    v2f U1r1 = { A1.z,  A1.x }, U1i1 = { A1.w, -A1.y };
#pragma unroll
    for (int j = 0; j < 4; ++j) {
        v2f U0r = (j & 1) ? U0r1 : U0r0;
        v2f U0i = (j & 1) ? U0i1 : U0i0;
        v2f U1r = (j & 1) ? U1r1 : U1r0;
        v2f U1i = (j & 1) ? U1i1 : U1i0;
        v2f A0r = xr[j].xx, A0i = xi[j].xx, A1r = xr[j].yy, A1i = xi[j].yy;
        xr[j] = U0r*A0r - U0i*A0i + U1r*A1r - U1i*A1i;
        xi[j] = U0r*A0i + U0i*A0r + U1r*A1i + U1i*A1r;
    }
}

// ---- fused cross gate: ctrl lane bit CB selects U0/U1; tgt lane bit LB ----
template<int CB, int LB>
__device__ __forceinline__ void fusedC_crossU(v2f (&xr)[4], v2f (&xi)[4],
                                              const float* __restrict__ m, int lane) {
    const v4f A0 = *(const v4f*)m;
    const v4f A1 = *(const v4f*)(m + 4);
    const bool ctrl = (lane >> CB) & 1;
    v4f A;
    A.x = ctrl ? A1.x : A0.x;  A.y = ctrl ? A1.y : A0.y;
    A.z = ctrl ? A1.z : A0.z;  A.w = ctrl ? A1.w : A0.w;
    SET_U(A)
    const int bit = (lane >> LB) & 1;
    const float Csr = u00r,  Cpi = u01i;
    const float Csi = bit ? -u00i : u00i;
    const float Cpr = bit ? -u01r : u01r;
#pragma unroll
    for (int j = 0; j < 4; ++j) {
        v2f pr = xmv2(xr[j], 1 << LB);
        v2f pi = xmv2(xi[j], 1 << LB);
        v2f ar = xr[j], ai = xi[j];
        xr[j] = sp(Csr)*ar - sp(Csi)*ai + sp(Cpr)*pr - sp(Cpi)*pi;
        xi[j] = sp(Csr)*ai + sp(Csi)*ar + sp(Cpr)*pi + sp(Cpi)*pr;
    }
}

// ---- G6·C56 on j bit1 (wire6), ctrl = lane bit0 (wire5) ----
__device__ __forceinline__ void fusedC_j1U(v2f (&xr)[4], v2f (&xi)[4],
                                           const float* __restrict__ m, int lane) {
    const v4f A0 = *(const v4f*)m;
    const v4f A1 = *(const v4f*)(m + 4);
    const bool ctrl = lane & 1;
    v4f A;
    A.x = ctrl ? A1.x : A0.x;  A.y = ctrl ? A1.y : A0.y;
    A.z = ctrl ? A1.z : A0.z;  A.w = ctrl ? A1.w : A0.w;
    SET_U(A)
#pragma unroll
    for (int j = 0; j < 2; ++j) {
        const int q = j | 2;
        v2f a0r = xr[j], a0i = xi[j], a1r = xr[q], a1i = xi[q];
        xr[j] = sp(u00r)*a0r - sp(u00i)*a0i + sp(u01r)*a1r - sp(u01i)*a1i;
        xi[j] = sp(u00r)*a0i + sp(u00i)*a0r + sp(u01r)*a1i + sp(u01i)*a1r;
        xr[q] = sp(-u01r)*a0r - sp(u01i)*a0i + sp(u00r)*a1r + sp(u00i)*a1i;
        xi[q] = sp(-u01r)*a0i + sp(u01i)*a0r + sp(u00r)*a1i - sp(u00i)*a1r;
    }
}

// ---- CRX helpers (layer-0 ring + final C80) ----
template<int CB, int M>
__device__ __forceinline__ void crx_dpp(v2f (&xr)[4], v2f (&xi)[4], float c, float s, int lane) {
    const bool ctrl = (lane >> CB) & 1;
    const float ce = ctrl ? c : 1.f;
    const float se = ctrl ? s : 0.f;
#pragma unroll
    for (int j = 0; j < 4; ++j) {
        v2f pr = xmv2(xr[j], M);
        v2f pi = xmv2(xi[j], M);
        xr[j] = sp(ce)*xr[j] + sp(se)*pi;
        xi[j] = sp(ce)*xi[j] - sp(se)*pr;
    }
}
__device__ __forceinline__ void crx_pair_s(v2f (&xr)[4], v2f (&xi)[4], float ce, float se) {
#pragma unroll
    for (int p = 0; p < 4; p += 2) {
        const int q = p + 1;
        v2f a0r = xr[p], a0i = xi[p], a1r = xr[q], a1i = xi[q];
        xr[p] = sp(ce)*a0r + sp(se)*a1i;
        xi[p] = sp(ce)*a0i - sp(se)*a1r;
        xr[q] = sp(ce)*a1r + sp(se)*a0i;
        xi[q] = sp(ce)*a1i - sp(se)*a0r;
    }
}
__device__ __forceinline__ void crx_pair_c(v2f (&xr)[4], v2f (&xi)[4], float c, float s) {
    const v2f cev = {1.f, c};
    const v2f sev = {0.f, s};
#pragma unroll
    for (int p = 0; p < 4; p += 2) {
        const int q = p + 1;
        v2f a0r = xr[p], a0i = xi[p], a1r = xr[q], a1i = xi[q];
        xr[p] = cev*a0r + sev*a1i;
        xi[p] = cev*a0i - sev*a1r;
        xr[q] = cev*a1r + sev*a0i;
        xi[q] = cev*a1i - sev*a0r;
    }
}
__device__ __forceinline__ void crx_l_j1(v2f (&xr)[4], v2f (&xi)[4], float c, float s, int lane) {
    const bool ctrl = lane & 1;
    const float ce = ctrl ? c : 1.f;
    const float se = ctrl ? s : 0.f;
#pragma unroll
    for (int j = 0; j < 2; ++j) {
        const int q = j | 2;
        v2f a0r = xr[j], a0i = xi[j], a1r = xr[q], a1i = xi[q];
        xr[j] = sp(ce)*a0r + sp(se)*a1i;
        xi[j] = sp(ce)*a0i - sp(se)*a1r;
        xr[q] = sp(ce)*a1r + sp(se)*a0i;
        xi[q] = sp(ce)*a1i - sp(se)*a0r;
    }
}
__device__ __forceinline__ void crx_j1_j0(v2f (&xr)[4], v2f (&xi)[4], float c, float s) {
    v2f a0r = xr[2], a0i = xi[2], a1r = xr[3], a1i = xi[3];
    xr[2] = sp(c)*a0r + sp(s)*a1i;
    xi[2] = sp(c)*a0i - sp(s)*a1r;
    xr[3] = sp(c)*a1r + sp(s)*a0i;
    xi[3] = sp(c)*a1i - sp(s)*a0r;
}
__device__ __forceinline__ void crx_j0_c(v2f (&xr)[4], v2f (&xi)[4], float c, float s) {
#pragma unroll
    for (int j = 1; j < 4; j += 2) {
        v2f vr = xr[j], vi = xi[j];
        xr[j] = sp(c)*vr + sp(s)*vi.yx;
        xi[j] = sp(c)*vi - sp(s)*vr.yx;
    }
}

__global__ __launch_bounds__(256) void qmlp_kernel(
    const float* __restrict__ x, const float* __restrict__ rot_w,
    const float* __restrict__ crx_w, const float* __restrict__ fc_w,
    const float* __restrict__ fc_b, float* __restrict__ out, int B)
{
    __shared__ __align__(16) float Usm[4][NL][NQ][8];   // per-sample fused gate matrices
    __shared__ __align__(16) float crxs[NL * NQ * 2];
    __shared__ float fcw[NC * NQ];
    __shared__ float fcbs[NC];

    const int tid = threadIdx.x;
    if (tid < NL * NQ) {
        float sc, cc; sincosf(0.5f * crx_w[tid], &sc, &cc);
        crxs[tid * 2 + 0] = cc; crxs[tid * 2 + 1] = sc;
    }
    if (tid < NC * NQ) fcw[tid] = fc_w[tid];
    if (tid < NC) fcbs[tid] = fc_b[tid];
    // per-sample gate matrix precompute: one (sample, n, w) per thread
    if (tid < 4 * NL * NQ) {
        const int s = tid / (NL * NQ);
        const int g = tid % (NL * NQ);
        const int n = g / NQ, w = g % NQ;
        const int b = blockIdx.x * 4 + s;
        if (b < B) {
            const float phi = rot_w[g * 3 + 0];
            const float th  = rot_w[g * 3 + 1];
            const float om  = rot_w[g * 3 + 2];
            float st, ct; sincosf(0.5f * th, &st, &ct);
            float spo, cpo; sincosf(0.5f * (phi + om), &spo, &cpo);
            float smo, cmo; sincosf(0.5f * (phi - om), &smo, &cmo);
            const float m00r =  ct * cpo, m00i = -ct * spo;
            const float m01r = -st * cmo, m01i = -st * smo;
            float sX, cX; sincosf(0.5f * x[b * NQ + w], &sX, &cX);
            // U0 = M0 * RX(x_w)
            const float a00r = m00r*cX + sX*m01i, a00i = m00i*cX - sX*m01r;
            const float a01r = m01r*cX + sX*m00i, a01i = m01i*cX - sX*m00r;
            float* o = &Usm[s][n][w][0];
            if (w == 0) {
                if (n == 0) {
                    o[0]=a00r; o[1]=a00i; o[2]=a01r; o[3]=a01i;
                    o[4]=a00r; o[5]=a00i; o[6]=a01r; o[7]=a01i;
                } else {
                    float sq, cq; sincosf(0.5f * crx_w[(n - 1) * NQ + 8], &sq, &cq);
                    // comp1 matrix = U0 * RX(th8(n-1))  (right-mult = HALF_U form on U0)
                    const float b00r = a00r*cq + sq*a01i, b00i = a00i*cq - sq*a01r;
                    const float b01r = a01r*cq + sq*a00i, b01i = a01i*cq - sq*a00r;
                    o[0]=a00r; o[1]=b00r; o[2]=a00i; o[3]=b00i;    // interleaved per-comp
                    o[4]=a01r; o[5]=b01r; o[6]=a01i; o[7]=b01i;
                }
            } else {
                float sq, cq; sincosf(0.5f * crx_w[n * NQ + (w - 1)], &sq, &cq);
                // M1 = RX(q) * M0
                const float n00r = cq*m00r + sq*m01i, n00i = cq*m00i + sq*m01r;
                const float n01r = cq*m01r - sq*m00i, n01i = cq*m01i - sq*m00r;
                // U1 = M1 * RX(x_w)
                const float b00r = n00r*cX + sX*n01i, b00i = n00i*cX - sX*n01r;
                const float b01r = n01r*cX + sX*n00i, b01i = n01i*cX - sX*n00r;
                o[0]=a00r; o[1]=a00i; o[2]=a01r; o[3]=a01i;
                o[4]=b00r; o[5]=b00i; o[6]=b01r; o[7]=b01i;
            }
        }
    }
    __syncthreads();

    const int lane = tid & 63;
    const int s = tid >> 6;
    const int b = blockIdx.x * 4 + s;
    if (b >= B) return;
    const float* Us = &Usm[s][0][0][0];   // gate (n,w) at Us + (n*9+w)*8

    v2f xr[4], xi[4];

    // ---- Layer 0 single-qubit block on |0..0>: direct product state ----
    {
        float ar = 1.f, ai = 0.f;
#pragma unroll
        for (int w = 0; w < 6; ++w) {
            const v4f A = *(const v4f*)(Us + w * 8);
            int bit = (lane >> (5 - w)) & 1;
            float vr = bit ? -A.z : A.x;       // col0 = (u00, -conj u01)
            float vi = bit ?  A.w : A.y;
            float nr = ar * vr - ai * vi;
            float ni = ar * vi + ai * vr;
            ar = nr; ai = ni;
        }
        float vr67[2][2], vi67[2][2];
#pragma unroll
        for (int q = 0; q < 2; ++q) {
            const v4f A = *(const v4f*)(Us + (6 + q) * 8);
            vr67[q][0] = A.x;  vi67[q][0] = A.y;
            vr67[q][1] = -A.z; vi67[q][1] = A.w;
        }
        float t6r[2], t6i[2];
#pragma unroll
        for (int bb = 0; bb < 2; ++bb) {
            t6r[bb] = ar * vr67[0][bb] - ai * vi67[0][bb];
            t6i[bb] = ar * vi67[0][bb] + ai * vr67[0][bb];
        }
        float t67r[4], t67i[4];
#pragma unroll
        for (int j = 0; j < 4; ++j) {
            int b6 = j >> 1, b7 = j & 1;
            t67r[j] = t6r[b6] * vr67[1][b7] - t6i[b6] * vi67[1][b7];
            t67i[j] = t6r[b6] * vi67[1][b7] + t6i[b6] * vr67[1][b7];
        }
        {
            const v4f A = *(const v4f*)(Us + 8 * 8);
            v2f V8r = { A.x, -A.z };
            v2f V8i = { A.y,  A.w };
#pragma unroll
            for (int j = 0; j < 4; ++j) {
                xr[j] = sp(t67r[j])*V8r - sp(t67i[j])*V8i;
                xi[j] = sp(t67r[j])*V8i + sp(t67i[j])*V8r;
            }
        }
    }

    // ---- Layer 0 CRX ring (C01..C78; C80 deferred into layer 1's G0) ----
    {
        const float* C = crxs;
        state_swap(xr, xi, 16);
        {
            const bool ctrl = (lane >> 5) & 1;
            crx_pair_s(xr, xi, ctrl ? C[0] : 1.f, ctrl ? C[1] : 0.f);   // C01
        }
        state_swap(xr, xi, 16);
        crx_dpp<4, 8>(xr, xi, C[2],  C[3],  lane);  // C12
        crx_dpp<3, 4>(xr, xi, C[4],  C[5],  lane);  // C23
        crx_dpp<2, 2>(xr, xi, C[6],  C[7],  lane);  // C34
        crx_dpp<1, 1>(xr, xi, C[8],  C[9],  lane);  // C45
        crx_l_j1     (xr, xi, C[10], C[11], lane);  // C56
        crx_j1_j0    (xr, xi, C[12], C[13]);        // C67
        crx_j0_c     (xr, xi, C[14], C[15]);        // C78
        state_swap(xr, xi, 32);                      // enter split-32 (C80 fused ahead)
    }

    // ---- Layers 1..4: 9 fused gates each; enter in split-32 space ----
    for (int n = 1; n < NL; ++n) {
        const float* Un = Us + n * NQ * 8;
        rot_pair_v2pk(xr, xi, Un + 0 * 8);                     // G0·C80(n-1)
        state_swap(xr, xi, 32);
        state_swap(xr, xi, 16);
        rot_pair_selU(xr, xi, Un + 1 * 8, (lane >> 5) & 1);    // G1·C01
        state_swap(xr, xi, 16);
        fusedC_crossU<4, 3>(xr, xi, Un + 2 * 8, lane);         // G2·C12
        fusedC_crossU<3, 2>(xr, xi, Un + 3 * 8, lane);         // G3·C23
        fusedC_crossU<2, 1>(xr, xi, Un + 4 * 8, lane);         // G4·C34
        fusedC_crossU<1, 0>(xr, xi, Un + 5 * 8, lane);         // G5·C45
        fusedC_j1U(xr, xi, Un + 6 * 8, lane);                  // G6·C56
        rot_pair_dualU(xr, xi, Un + 7 * 8);                    // G7·C67
        rot_comp_dualU(xr, xi, Un + 8 * 8);                    // G8·C78
        state_swap(xr, xi, 32);                                // split-32 for next G0
    }
    // final layer-4 C80, then restore
    crx_pair_c(xr, xi, crxs[(4 * NQ + 8) * 2], crxs[(4 * NQ + 8) * 2 + 1]);
    state_swap(xr, xi, 32);

    // ---- probabilities and <Z_w> ----
    v2f P[4];
#pragma unroll
    for (int j = 0; j < 4; ++j) P[j] = xr[j]*xr[j] + xi[j]*xi[j];
    float ps[4];
#pragma unroll
    for (int j = 0; j < 4; ++j) ps[j] = P[j].x + P[j].y;
    float psum = ps[0] + ps[1] + ps[2] + ps[3];

    float t = psum;
    float d[6];
#pragma unroll
    for (int bb = 0; bb < 6; ++bb) {
        if (bb < 4) {
#pragma unroll
            for (int jj = 0; jj < 6; ++jj)
                if (jj < bb) d[jj] += xmove(d[jj], 1 << bb);
            float o = xmove(t, 1 << bb);
            d[bb] = ((lane >> bb) & 1) ? (o - t) : (t - o);
            t += o;
        } else {
#pragma unroll
            for (int jj = 0; jj < 6; ++jj)
                if (jj < bb) { float h, l; swpm(d[jj], 1 << bb, h, l); d[jj] = h + l; }
            float h, l; swpm(t, 1 << bb, h, l);
            d[bb] = l - h;
            t = h + l;
        }
    }
    float e6 = (ps[0] + ps[1]) - (ps[2] + ps[3]);
    float e7 = (ps[0] + ps[2]) - (ps[1] + ps[3]);
    float e8 = (P[0].x - P[0].y) + (P[1].x - P[1].y)
             + (P[2].x - P[2].y) + (P[3].x - P[3].y);
#pragma unroll
    for (int m = 1; m < 16; m <<= 1) {
        e6 += xmove(e6, m); e7 += xmove(e7, m); e8 += xmove(e8, m);
    }
    {
        float h, l;
        swpm(e6, 16, h, l); e6 = h + l;  swpm(e6, 32, h, l); e6 = h + l;
        swpm(e7, 16, h, l); e7 = h + l;  swpm(e7, 32, h, l); e7 = h + l;
        swpm(e8, 16, h, l); e8 = h + l;  swpm(e8, 32, h, l); e8 = h + l;
    }

    float ev[NQ];
#pragma unroll
    for (int w = 0; w < 6; ++w) ev[w] = d[5 - w];
    ev[6] = e6; ev[7] = e7; ev[8] = e8;

    // ---- linear head + log_softmax ----
    float lval = -INFINITY;
    if (lane < NC) {
        float dd = fcbs[lane];
        const float* fw = fcw + lane * NQ;
#pragma unroll
        for (int w = 0; w < NQ; ++w) dd += ev[w] * fw[w];
        lval = dd;
    }
    float mx = lval;
    mx = fmaxf(mx, xmove(mx, 1));
    mx = fmaxf(mx, xmove(mx, 2));
    mx = fmaxf(mx, xmove(mx, 4));
    mx = fmaxf(mx, xmove(mx, 8));
    float e = (lane < NC) ? expf(lval - mx) : 0.f;
    float se = e;
    se += xmove(se, 1); se += xmove(se, 2); se += xmove(se, 4); se += xmove(se, 8);
    if (lane < NC) out[b * NC + lane] = lval - mx - logf(se);
}

extern "C" void kernel_launch(void* const* d_in, const int* in_sizes, int n_in,
                              void* d_out, int out_size, void* d_ws, size_t ws_size,
                              hipStream_t stream) {
    const float* x     = (const float*)d_in[0];
    const float* rot_w = (const float*)d_in[1];
    const float* crx_w = (const float*)d_in[2];
    const float* fc_w  = (const float*)d_in[3];
    const float* fc_b  = (const float*)d_in[4];
    float* out = (float*)d_out;
    const int B = in_sizes[0] / NQ;
    const int blocks = (B + 3) / 4;
    qmlp_kernel<<<blocks, 256, 0, stream>>>(x, rot_w, crx_w, fc_w, fc_b, out, B);
}

// Round 13
// 26.956 us; speedup vs baseline: 1.6473x; 1.0050x over previous
//
#include <hip/hip_runtime.h>
#include <math.h>

#define NQ 9
#define NL 5
#define NC 10

typedef float v2f __attribute__((ext_vector_type(2)));
typedef float v4f __attribute__((ext_vector_type(4)));

__device__ __forceinline__ v2f sp(float x) { v2f r; r.x = x; r.y = x; return r; }

// ---- gfx950 permlane pair swap: (a,b) -> (S0 = bitM=0 side, S1 = bitM=1 side) ----
__device__ __forceinline__ void plswap(float& a, float& b, int mask) {
    if (mask == 32) {
        auto r = __builtin_amdgcn_permlane32_swap(__float_as_int(a), __float_as_int(b), false, false);
        a = __int_as_float(r[0]); b = __int_as_float(r[1]);
    } else {
        auto r = __builtin_amdgcn_permlane16_swap(__float_as_int(a), __float_as_int(b), false, false);
        a = __int_as_float(r[0]); b = __int_as_float(r[1]);
    }
}
__device__ __forceinline__ void plswap2(v2f& a, v2f& b, int mask) {
    float ax = a.x, bx = b.x, ay = a.y, by = b.y;
    plswap(ax, bx, mask); plswap(ay, by, mask);
    a.x = ax; a.y = ay; b.x = bx; b.y = by;
}
__device__ __forceinline__ void state_swap(v2f (&xr)[4], v2f (&xi)[4], int mask) {
    plswap2(xr[0], xr[1], mask); plswap2(xr[2], xr[3], mask);
    plswap2(xi[0], xi[1], mask); plswap2(xi[2], xi[3], mask);
}

// ---- broadcast swpm (epilogue only): r[0]=lo-broadcast, r[1]=hi-broadcast ----
__device__ __forceinline__ void swpm(float x, int mask, float& hi, float& lo) {
    if (mask == 32) {
        auto r = __builtin_amdgcn_permlane32_swap(__float_as_int(x), __float_as_int(x), false, false);
        lo = __int_as_float(r[0]); hi = __int_as_float(r[1]);
    } else {
        auto r = __builtin_amdgcn_permlane16_swap(__float_as_int(x), __float_as_int(x), false, false);
        lo = __int_as_float(r[0]); hi = __int_as_float(r[1]);
    }
}

// XOR-lane exchange masks 1,2,4,8 — DPP (VALU).
__device__ __forceinline__ float xmove(float x, int mask) {
    if (mask == 1)
        return __int_as_float(__builtin_amdgcn_update_dpp(0, __float_as_int(x), 0xB1, 0xF, 0xF, true));
    if (mask == 2)
        return __int_as_float(__builtin_amdgcn_update_dpp(0, __float_as_int(x), 0x4E, 0xF, 0xF, true));
    if (mask == 4) {
        int t = __builtin_amdgcn_update_dpp(0, __float_as_int(x), 0x104, 0xF, 0x5, false);
        t = __builtin_amdgcn_update_dpp(t, __float_as_int(x), 0x114, 0xF, 0xA, false);
        return __int_as_float(t);
    }
    return __int_as_float(__builtin_amdgcn_update_dpp(0, __float_as_int(x), 0x128, 0xF, 0xF, true));
}
__device__ __forceinline__ v2f xmv2(v2f v, int mask) {
    v2f r; r.x = xmove(v.x, mask); r.y = xmove(v.y, mask); return r;
}

// State packing: lane owns 8 amps as 4 x float2; amp = (j<<1)|comp.
// wire w -> bit 8-w: wires 0..5 -> lane bits 5..0; wire6 -> j bit1; wire7 -> j bit0; wire8 -> comp.
// Precomputed per (sample, n, w): SU(2) matrices as (u00r,u00i,u01r,u01i):
//   slot[0..3] = U0 = M0*RX(x_w), slot[4..7] = U1 = (RX(th_{w-1})*M0)*RX(x_w);
//   w==0,n>=1: interleaved per-comp packing {u00r0,u00r1,u00i0,u00i1,u01r0,u01r1,u01i0,u01i1}
//   with comp1 matrix = U0*RX(th8(n-1)).
#define SET_U(Uv) float u00r=(Uv).x, u00i=(Uv).y, u01r=(Uv).z, u01i=(Uv).w;

#define PAIR_BODY(p, q)                                                       \
    {                                                                         \
        v2f a0r = xr[p], a0i = xi[p], a1r = xr[q], a1i = xi[q];               \
        xr[p] = sp(u00r)*a0r - sp(u00i)*a0i + sp(u01r)*a1r - sp(u01i)*a1i;    \
        xi[p] = sp(u00r)*a0i + sp(u00i)*a0r + sp(u01r)*a1i + sp(u01i)*a1r;    \
        xr[q] = sp(-u01r)*a0r - sp(u01i)*a0i + sp(u00r)*a1r + sp(u00i)*a1i;   \
        xi[q] = sp(-u01r)*a0i + sp(u01i)*a0r + sp(u00r)*a1i - sp(u00i)*a1r;   \
    }

// ---- G7·C67: pair axis = wire7; pair(0,1) -> U0, pair(2,3) -> U1 ----
__device__ __forceinline__ void rot_pair_dualU(v2f (&xr)[4], v2f (&xi)[4],
                                               const float* __restrict__ m) {
    const v4f A0 = *(const v4f*)m;
    const v4f A1 = *(const v4f*)(m + 4);
    { SET_U(A0) PAIR_BODY(0, 1) }
    { SET_U(A1) PAIR_BODY(2, 3) }
}

// ---- G1·C01: split-16 pair gate, matrix chosen by ctrl via LDS ADDRESS select ----
__device__ __forceinline__ void rot_pair_selU(v2f (&xr)[4], v2f (&xi)[4],
                                              const float* __restrict__ m, bool ctrl) {
    const v4f A = *(const v4f*)(m + (ctrl ? 4 : 0));
    SET_U(A)
    PAIR_BODY(0, 1)
    PAIR_BODY(2, 3)
}

// ---- G0·C80(prev): split-32 pair gate, per-component matrices (pre-interleaved) ----
__device__ __forceinline__ void rot_pair_v2pk(v2f (&xr)[4], v2f (&xi)[4],
                                              const float* __restrict__ m) {
    const v4f P0 = *(const v4f*)m;        // {u00r0,u00r1,u00i0,u00i1}
    const v4f P1 = *(const v4f*)(m + 4);  // {u01r0,u01r1,u01i0,u01i1}
    v2f u00r = P0.xy, u00i = P0.zw, u01r = P1.xy, u01i = P1.zw;
#pragma unroll
    for (int p = 0; p < 4; p += 2) {
        const int q = p + 1;
        v2f a0r = xr[p], a0i = xi[p], a1r = xr[q], a1i = xi[q];
        xr[p] = u00r*a0r - u00i*a0i + u01r*a1r - u01i*a1i;
        xi[p] = u00r*a0i + u00i*a0r + u01r*a1i + u01i*a1r;
        xr[q] = -u01r*a0r - u01i*a0i + u00r*a1r + u00i*a1i;
        xi[q] = -u01r*a0i + u01i*a0r + u00r*a1i - u00i*a1r;
    }
}

// ---- G8·C78: component axis; even j -> U0, odd j -> U1 ----
__device__ __forceinline__ void rot_comp_dualU(v2f (&xr)[4], v2f (&xi)[4],
                                               const float* __restrict__ m) {
    const v4f A0 = *(const v4f*)m;
    const v4f A1 = *(const v4f*)(m + 4);
    v2f U0r0 = { A0.x, -A0.z }, U0i0 = { A0.y,  A0.w };
    v2f U1r0 = { A0.z,  A0.x }, U1i0 = { A0.w, -A0.y };
    v2f U0r1 = { A1.x, -A1.z }, U0i1 = { A1.y,  A1.w };
    v2f U1r1 = { A1.z,  A1.x }, U1i1 = { A1.w, -A1.y };
#pragma unroll
    for (int j = 0; j < 4; ++j) {
        v2f U0r = (j & 1) ? U0r1 : U0r0;
        v2f U0i = (j & 1) ? U0i1 : U0i0;
        v2f U1r = (j & 1) ? U1r1 : U1r0;
        v2f U1i = (j & 1) ? U1i1 : U1i0;
        v2f A0r = xr[j].xx, A0i = xi[j].xx, A1r = xr[j].yy, A1i = xi[j].yy;
        xr[j] = U0r*A0r - U0i*A0i + U1r*A1r - U1i*A1i;
        xi[j] = U0r*A0i + U0i*A0r + U1r*A1i + U1i*A1r;
    }
}

// ---- fused cross gate: ctrl selects U0/U1 via LDS ADDRESS; tgt lane bit LB ----
template<int CB, int LB>
__device__ __forceinline__ void fusedC_crossU(v2f (&xr)[4], v2f (&xi)[4],
                                              const float* __restrict__ m, int lane) {
    const bool ctrl = (lane >> CB) & 1;
    const v4f A = *(const v4f*)(m + (ctrl ? 4 : 0));
    SET_U(A)
    const int bit = (lane >> LB) & 1;
    const float Csr = u00r,  Cpi = u01i;
    const float Csi = bit ? -u00i : u00i;
    const float Cpr = bit ? -u01r : u01r;
#pragma unroll
    for (int j = 0; j < 4; ++j) {
        v2f pr = xmv2(xr[j], 1 << LB);
        v2f pi = xmv2(xi[j], 1 << LB);
        v2f ar = xr[j], ai = xi[j];
        xr[j] = sp(Csr)*ar - sp(Csi)*ai + sp(Cpr)*pr - sp(Cpi)*pi;
        xi[j] = sp(Csr)*ai + sp(Csi)*ar + sp(Cpr)*pi + sp(Cpi)*pr;
    }
}

// ---- G6·C56 on j bit1 (wire6), ctrl = lane bit0 (wire5), address select ----
__device__ __forceinline__ void fusedC_j1U(v2f (&xr)[4], v2f (&xi)[4],
                                           const float* __restrict__ m, int lane) {
    const bool ctrl = lane & 1;
    const v4f A = *(const v4f*)(m + (ctrl ? 4 : 0));
    SET_U(A)
#pragma unroll
    for (int j = 0; j < 2; ++j) {
        const int q = j | 2;
        v2f a0r = xr[j], a0i = xi[j], a1r = xr[q], a1i = xi[q];
        xr[j] = sp(u00r)*a0r - sp(u00i)*a0i + sp(u01r)*a1r - sp(u01i)*a1i;
        xi[j] = sp(u00r)*a0i + sp(u00i)*a0r + sp(u01r)*a1i + sp(u01i)*a1r;
        xr[q] = sp(-u01r)*a0r - sp(u01i)*a0i + sp(u00r)*a1r + sp(u00i)*a1i;
        xi[q] = sp(-u01r)*a0i + sp(u01i)*a0r + sp(u00r)*a1i - sp(u00i)*a1r;
    }
}

// ---- CRX helpers (layer-0 ring + final C80) ----
template<int CB, int M>
__device__ __forceinline__ void crx_dpp(v2f (&xr)[4], v2f (&xi)[4], float c, float s, int lane) {
    const bool ctrl = (lane >> CB) & 1;
    const float ce = ctrl ? c : 1.f;
    const float se = ctrl ? s : 0.f;
#pragma unroll
    for (int j = 0; j < 4; ++j) {
        v2f pr = xmv2(xr[j], M);
        v2f pi = xmv2(xi[j], M);
        xr[j] = sp(ce)*xr[j] + sp(se)*pi;
        xi[j] = sp(ce)*xi[j] - sp(se)*pr;
    }
}
__device__ __forceinline__ void crx_pair_s(v2f (&xr)[4], v2f (&xi)[4], float ce, float se) {
#pragma unroll
    for (int p = 0; p < 4; p += 2) {
        const int q = p + 1;
        v2f a0r = xr[p], a0i = xi[p], a1r = xr[q], a1i = xi[q];
        xr[p] = sp(ce)*a0r + sp(se)*a1i;
        xi[p] = sp(ce)*a0i - sp(se)*a1r;
        xr[q] = sp(ce)*a1r + sp(se)*a0i;
        xi[q] = sp(ce)*a1i - sp(se)*a0r;
    }
}
__device__ __forceinline__ void crx_pair_c(v2f (&xr)[4], v2f (&xi)[4], float c, float s) {
    const v2f cev = {1.f, c};
    const v2f sev = {0.f, s};
#pragma unroll
    for (int p = 0; p < 4; p += 2) {
        const int q = p + 1;
        v2f a0r = xr[p], a0i = xi[p], a1r = xr[q], a1i = xi[q];
        xr[p] = cev*a0r + sev*a1i;
        xi[p] = cev*a0i - sev*a1r;
        xr[q] = cev*a1r + sev*a0i;
        xi[q] = cev*a1i - sev*a0r;
    }
}
__device__ __forceinline__ void crx_l_j1(v2f (&xr)[4], v2f (&xi)[4], float c, float s, int lane) {
    const bool ctrl = lane & 1;
    const float ce = ctrl ? c : 1.f;
    const float se = ctrl ? s : 0.f;
#pragma unroll
    for (int j = 0; j < 2; ++j) {
        const int q = j | 2;
        v2f a0r = xr[j], a0i = xi[j], a1r = xr[q], a1i = xi[q];
        xr[j] = sp(ce)*a0r + sp(se)*a1i;
        xi[j] = sp(ce)*a0i - sp(se)*a1r;
        xr[q] = sp(ce)*a1r + sp(se)*a0i;
        xi[q] = sp(ce)*a1i - sp(se)*a0r;
    }
}
__device__ __forceinline__ void crx_j1_j0(v2f (&xr)[4], v2f (&xi)[4], float c, float s) {
    v2f a0r = xr[2], a0i = xi[2], a1r = xr[3], a1i = xi[3];
    xr[2] = sp(c)*a0r + sp(s)*a1i;
    xi[2] = sp(c)*a0i - sp(s)*a1r;
    xr[3] = sp(c)*a1r + sp(s)*a0i;
    xi[3] = sp(c)*a1i - sp(s)*a0r;
}
__device__ __forceinline__ void crx_j0_c(v2f (&xr)[4], v2f (&xi)[4], float c, float s) {
#pragma unroll
    for (int j = 1; j < 4; j += 2) {
        v2f vr = xr[j], vi = xi[j];
        xr[j] = sp(c)*vr + sp(s)*vi.yx;
        xi[j] = sp(c)*vi - sp(s)*vr.yx;
    }
}

__global__ __launch_bounds__(256) void qmlp_kernel(
    const float* __restrict__ x, const float* __restrict__ rot_w,
    const float* __restrict__ crx_w, const float* __restrict__ fc_w,
    const float* __restrict__ fc_b, float* __restrict__ out, int B)
{
    __shared__ __align__(16) float Usm[4][NL][NQ][8];   // per-sample fused gate matrices
    __shared__ __align__(16) float crxs[NL * NQ * 2];
    __shared__ float fcw[NC * NQ];
    __shared__ float fcbs[NC];

    const int tid = threadIdx.x;
    if (tid < NL * NQ) {
        float sc, cc; sincosf(0.5f * crx_w[tid], &sc, &cc);
        crxs[tid * 2 + 0] = cc; crxs[tid * 2 + 1] = sc;
    }
    if (tid < NC * NQ) fcw[tid] = fc_w[tid];
    if (tid < NC) fcbs[tid] = fc_b[tid];
    // per-sample gate matrix precompute: one (sample, n, w) per thread
    if (tid < 4 * NL * NQ) {
        const int s = tid / (NL * NQ);
        const int g = tid % (NL * NQ);
        const int n = g / NQ, w = g % NQ;
        const int b = blockIdx.x * 4 + s;
        if (b < B) {
            const float phi = rot_w[g * 3 + 0];
            const float th  = rot_w[g * 3 + 1];
            const float om  = rot_w[g * 3 + 2];
            float st, ct; sincosf(0.5f * th, &st, &ct);
            float spo, cpo; sincosf(0.5f * (phi + om), &spo, &cpo);
            float smo, cmo; sincosf(0.5f * (phi - om), &smo, &cmo);
            const float m00r =  ct * cpo, m00i = -ct * spo;
            const float m01r = -st * cmo, m01i = -st * smo;
            float sX, cX; sincosf(0.5f * x[b * NQ + w], &sX, &cX);
            // U0 = M0 * RX(x_w)
            const float a00r = m00r*cX + sX*m01i, a00i = m00i*cX - sX*m01r;
            const float a01r = m01r*cX + sX*m00i, a01i = m01i*cX - sX*m00r;
            float* o = &Usm[s][n][w][0];
            if (w == 0) {
                if (n == 0) {
                    o[0]=a00r; o[1]=a00i; o[2]=a01r; o[3]=a01i;
                    o[4]=a00r; o[5]=a00i; o[6]=a01r; o[7]=a01i;
                } else {
                    float sq, cq; sincosf(0.5f * crx_w[(n - 1) * NQ + 8], &sq, &cq);
                    // comp1 matrix = U0 * RX(th8(n-1))
                    const float b00r = a00r*cq + sq*a01i, b00i = a00i*cq - sq*a01r;
                    const float b01r = a01r*cq + sq*a00i, b01i = a01i*cq - sq*a00r;
                    o[0]=a00r; o[1]=b00r; o[2]=a00i; o[3]=b00i;    // interleaved per-comp
                    o[4]=a01r; o[5]=b01r; o[6]=a01i; o[7]=b01i;
                }
            } else {
                float sq, cq; sincosf(0.5f * crx_w[n * NQ + (w - 1)], &sq, &cq);
                // M1 = RX(q) * M0
                const float n00r = cq*m00r + sq*m01i, n00i = cq*m00i + sq*m01r;
                const float n01r = cq*m01r - sq*m00i, n01i = cq*m01i - sq*m00r;
                // U1 = M1 * RX(x_w)
                const float b00r = n00r*cX + sX*n01i, b00i = n00i*cX - sX*n01r;
                const float b01r = n01r*cX + sX*n00i, b01i = n01i*cX - sX*n00r;
                o[0]=a00r; o[1]=a00i; o[2]=a01r; o[3]=a01i;
                o[4]=b00r; o[5]=b00i; o[6]=b01r; o[7]=b01i;
            }
        }
    }
    __syncthreads();

    const int lane = tid & 63;
    const int s = tid >> 6;
    const int b = blockIdx.x * 4 + s;
    if (b >= B) return;
    const float* Us = &Usm[s][0][0][0];   // gate (n,w) at Us + (n*9+w)*8

    v2f xr[4], xi[4];

    // ---- Layer 0 single-qubit block on |0..0>: direct product state ----
    {
        float ar = 1.f, ai = 0.f;
#pragma unroll
        for (int w = 0; w < 6; ++w) {
            const v4f A = *(const v4f*)(Us + w * 8);
            int bit = (lane >> (5 - w)) & 1;
            float vr = bit ? -A.z : A.x;       // col0 = (u00, -conj u01)
            float vi = bit ?  A.w : A.y;
            float nr = ar * vr - ai * vi;
            float ni = ar * vi + ai * vr;
            ar = nr; ai = ni;
        }
        float vr67[2][2], vi67[2][2];
#pragma unroll
        for (int q = 0; q < 2; ++q) {
            const v4f A = *(const v4f*)(Us + (6 + q) * 8);
            vr67[q][0] = A.x;  vi67[q][0] = A.y;
            vr67[q][1] = -A.z; vi67[q][1] = A.w;
        }
        float t6r[2], t6i[2];
#pragma unroll
        for (int bb = 0; bb < 2; ++bb) {
            t6r[bb] = ar * vr67[0][bb] - ai * vi67[0][bb];
            t6i[bb] = ar * vi67[0][bb] + ai * vr67[0][bb];
        }
        float t67r[4], t67i[4];
#pragma unroll
        for (int j = 0; j < 4; ++j) {
            int b6 = j >> 1, b7 = j & 1;
            t67r[j] = t6r[b6] * vr67[1][b7] - t6i[b6] * vi67[1][b7];
            t67i[j] = t6r[b6] * vi67[1][b7] + t6i[b6] * vr67[1][b7];
        }
        {
            const v4f A = *(const v4f*)(Us + 8 * 8);
            v2f V8r = { A.x, -A.z };
            v2f V8i = { A.y,  A.w };
#pragma unroll
            for (int j = 0; j < 4; ++j) {
                xr[j] = sp(t67r[j])*V8r - sp(t67i[j])*V8i;
                xi[j] = sp(t67r[j])*V8i + sp(t67i[j])*V8r;
            }
        }
    }

    // ---- Layer 0 CRX ring (C01..C78; C80 deferred into layer 1's G0) ----
    {
        const float* C = crxs;
        state_swap(xr, xi, 16);
        {
            const bool ctrl = (lane >> 5) & 1;
            crx_pair_s(xr, xi, ctrl ? C[0] : 1.f, ctrl ? C[1] : 0.f);   // C01
        }
        state_swap(xr, xi, 16);
        crx_dpp<4, 8>(xr, xi, C[2],  C[3],  lane);  // C12
        crx_dpp<3, 4>(xr, xi, C[4],  C[5],  lane);  // C23
        crx_dpp<2, 2>(xr, xi, C[6],  C[7],  lane);  // C34
        crx_dpp<1, 1>(xr, xi, C[8],  C[9],  lane);  // C45
        crx_l_j1     (xr, xi, C[10], C[11], lane);  // C56
        crx_j1_j0    (xr, xi, C[12], C[13]);        // C67
        crx_j0_c     (xr, xi, C[14], C[15]);        // C78
        state_swap(xr, xi, 32);                      // enter split-32 (C80 fused ahead)
    }

    // ---- Layers 1..4: 9 fused gates each; enter in split-32 space ----
    for (int n = 1; n < NL; ++n) {
        const float* Un = Us + n * NQ * 8;
        rot_pair_v2pk(xr, xi, Un + 0 * 8);                     // G0·C80(n-1)
        state_swap(xr, xi, 32);
        state_swap(xr, xi, 16);
        rot_pair_selU(xr, xi, Un + 1 * 8, (lane >> 5) & 1);    // G1·C01
        state_swap(xr, xi, 16);
        fusedC_crossU<4, 3>(xr, xi, Un + 2 * 8, lane);         // G2·C12
        fusedC_crossU<3, 2>(xr, xi, Un + 3 * 8, lane);         // G3·C23
        fusedC_crossU<2, 1>(xr, xi, Un + 4 * 8, lane);         // G4·C34
        fusedC_crossU<1, 0>(xr, xi, Un + 5 * 8, lane);         // G5·C45
        fusedC_j1U(xr, xi, Un + 6 * 8, lane);                  // G6·C56
        rot_pair_dualU(xr, xi, Un + 7 * 8);                    // G7·C67
        rot_comp_dualU(xr, xi, Un + 8 * 8);                    // G8·C78
        state_swap(xr, xi, 32);                                // split-32 for next G0
    }
    // final layer-4 C80, then restore
    crx_pair_c(xr, xi, crxs[(4 * NQ + 8) * 2], crxs[(4 * NQ + 8) * 2 + 1]);
    state_swap(xr, xi, 32);

    // ---- probabilities and <Z_w> ----
    v2f P[4];
#pragma unroll
    for (int j = 0; j < 4; ++j) P[j] = xr[j]*xr[j] + xi[j]*xi[j];
    float ps[4];
#pragma unroll
    for (int j = 0; j < 4; ++j) ps[j] = P[j].x + P[j].y;
    float psum = ps[0] + ps[1] + ps[2] + ps[3];

    float t = psum;
    float d[6];
#pragma unroll
    for (int bb = 0; bb < 6; ++bb) {
        if (bb < 4) {
#pragma unroll
            for (int jj = 0; jj < 6; ++jj)
                if (jj < bb) d[jj] += xmove(d[jj], 1 << bb);
            float o = xmove(t, 1 << bb);
            d[bb] = ((lane >> bb) & 1) ? (o - t) : (t - o);
            t += o;
        } else {
#pragma unroll
            for (int jj = 0; jj < 6; ++jj)
                if (jj < bb) { float h, l; swpm(d[jj], 1 << bb, h, l); d[jj] = h + l; }
            float h, l; swpm(t, 1 << bb, h, l);
            d[bb] = l - h;
            t = h + l;
        }
    }
    float e6 = (ps[0] + ps[1]) - (ps[2] + ps[3]);
    float e7 = (ps[0] + ps[2]) - (ps[1] + ps[3]);
    float e8 = (P[0].x - P[0].y) + (P[1].x - P[1].y)
             + (P[2].x - P[2].y) + (P[3].x - P[3].y);
#pragma unroll
    for (int m = 1; m < 16; m <<= 1) {
        e6 += xmove(e6, m); e7 += xmove(e7, m); e8 += xmove(e8, m);
    }
    {
        float h, l;
        swpm(e6, 16, h, l); e6 = h + l;  swpm(e6, 32, h, l); e6 = h + l;
        swpm(e7, 16, h, l); e7 = h + l;  swpm(e7, 32, h, l); e7 = h + l;
        swpm(e8, 16, h, l); e8 = h + l;  swpm(e8, 32, h, l); e8 = h + l;
    }

    float ev[NQ];
#pragma unroll
    for (int w = 0; w < 6; ++w) ev[w] = d[5 - w];
    ev[6] = e6; ev[7] = e7; ev[8] = e8;

    // ---- linear head + log_softmax (hw exp/log: err ~1e-6 << 6.6e-2 tol) ----
    float lval = -INFINITY;
    if (lane < NC) {
        float dd = fcbs[lane];
        const float* fw = fcw + lane * NQ;
#pragma unroll
        for (int w = 0; w < NQ; ++w) dd += ev[w] * fw[w];
        lval = dd;
    }
    float mx = lval;
    mx = fmaxf(mx, xmove(mx, 1));
    mx = fmaxf(mx, xmove(mx, 2));
    mx = fmaxf(mx, xmove(mx, 4));
    mx = fmaxf(mx, xmove(mx, 8));
    float e = (lane < NC) ? __expf(lval - mx) : 0.f;
    float se = e;
    se += xmove(se, 1); se += xmove(se, 2); se += xmove(se, 4); se += xmove(se, 8);
    if (lane < NC) out[b * NC + lane] = lval - mx - __logf(se);
}

extern "C" void kernel_launch(void* const* d_in, const int* in_sizes, int n_in,
                              void* d_out, int out_size, void* d_ws, size_t ws_size,
                              hipStream_t stream) {
    const float* x     = (const float*)d_in[0];
    const float* rot_w = (const float*)d_in[1];
    const float* crx_w = (const float*)d_in[2];
    const float* fc_w  = (const float*)d_in[3];
    const float* fc_b  = (const float*)d_in[4];
    float* out = (float*)d_out;
    const int B = in_sizes[0] / NQ;
    const int blocks = (B + 3) / 4;
    qmlp_kernel<<<blocks, 256, 0, stream>>>(x, rot_w, crx_w, fc_w, fc_b, out, B);
}